// Round 1
// baseline (2395.538 us; speedup 1.0000x reference)
//
#include <hip/hip_runtime.h>
#include <math.h>

#define B_ 32
#define S_ 2048
#define D_ 1024
#define H_ 1024
#define NEGV -1000000000000.0f
#define KC 32

// ---- Kernel 1: h_part[b,h] = sum_d ls[b,d] * W[h, d]  (Wh = W[:, :D])
__global__ __launch_bounds__(256) void k_hpart(const float* __restrict__ ls,
                                               const float* __restrict__ W,
                                               float* __restrict__ hp) {
    int bh = blockIdx.x * 256 + threadIdx.x;   // 32768 total
    int b = bh >> 10, h = bh & 1023;
    const float* lsr = ls + b * D_;
    const float* wr  = W + (size_t)h * (2 * D_);
    float acc = 0.f;
#pragma unroll 4
    for (int d = 0; d < D_; d += 4) {
        float4 a = *(const float4*)(lsr + d);
        float4 w = *(const float4*)(wr + d);
        acc += a.x * w.x + a.y * w.y + a.z * w.z + a.w * w.w;
    }
    hp[bh] = acc;
}

// ---- Kernel 2: fused scores GEMM
// scores[b,s] = sum_h tanh( sum_d enc[b,s,d]*W[h, D+d] + hp[b,h] + bias[h] ) * V[h]
// then masked: mask!=1 -> NEG
__global__ __launch_bounds__(256) void k_scores(const float* __restrict__ enc,
                                                const float* __restrict__ W,
                                                const float* __restrict__ hp,
                                                const float* __restrict__ bias,
                                                const float* __restrict__ V,
                                                const int* __restrict__ mask,
                                                float* __restrict__ scores_out) {
    __shared__ float As[KC][64];   // A transposed: As[k][row]
    __shared__ float Bs[KC][64];   // B transposed: Bs[k][n]
    int tid = threadIdx.x;
    int tx = tid & 15, ty = tid >> 4;
    int m0 = blockIdx.x * 64;      // global row (b*S + s)
    int b = m0 >> 11;              // 64 | 2048 so tiles never straddle b
    float rowsum[4] = {0.f, 0.f, 0.f, 0.f};

    for (int nb = 0; nb < H_ / 64; ++nb) {
        int n0 = nb * 64;
        float acc[4][4] = {};
        for (int kb = 0; kb < D_ / KC; ++kb) {
            int k0 = kb * KC;
            // stage A(64 x 32) and B(64 x 32), transposed into LDS
#pragma unroll
            for (int i = 0; i < 2; ++i) {
                int idx = tid + i * 256;      // 0..511
                int row = idx >> 3;           // 0..63
                int c4  = idx & 7;            // 0..7 (float4 index)
                float4 a = *(const float4*)(enc + (size_t)(m0 + row) * D_ + k0 + c4 * 4);
                int kk = c4 * 4;
                As[kk + 0][row] = a.x; As[kk + 1][row] = a.y;
                As[kk + 2][row] = a.z; As[kk + 3][row] = a.w;
                float4 w = *(const float4*)(W + (size_t)(n0 + row) * (2 * D_) + D_ + k0 + c4 * 4);
                Bs[kk + 0][row] = w.x; Bs[kk + 1][row] = w.y;
                Bs[kk + 2][row] = w.z; Bs[kk + 3][row] = w.w;
            }
            __syncthreads();
#pragma unroll
            for (int k = 0; k < KC; ++k) {
                float4 a4 = *(const float4*)&As[k][ty * 4];
                float4 b4 = *(const float4*)&Bs[k][tx * 4];
                float av[4] = {a4.x, a4.y, a4.z, a4.w};
                float bv[4] = {b4.x, b4.y, b4.z, b4.w};
#pragma unroll
                for (int r = 0; r < 4; ++r)
#pragma unroll
                    for (int c = 0; c < 4; ++c)
                        acc[r][c] += av[r] * bv[c];
            }
            __syncthreads();
        }
        // epilogue for this 64-wide n tile: tanh + V-weighted row partial
#pragma unroll
        for (int c = 0; c < 4; ++c) {
            int n = n0 + tx * 4 + c;
            float hb = hp[b * H_ + n] + bias[n];
            float vv = V[n];
#pragma unroll
            for (int r = 0; r < 4; ++r)
                rowsum[r] += tanhf(acc[r][c] + hb) * vv;
        }
    }
    // reduce across the 16 tx lanes (consecutive lanes within a wave)
#pragma unroll
    for (int r = 0; r < 4; ++r) {
        float v = rowsum[r];
        for (int off = 8; off; off >>= 1) v += __shfl_xor(v, off, 16);
        if (tx == 0) {
            int m = m0 + ty * 4 + r;
            scores_out[m] = (mask[m] == 1) ? v : NEGV;
        }
    }
}

// ---- Kernel 3: softmax over S per batch (reads masked scores)
__global__ __launch_bounds__(256) void k_softmax(const float* __restrict__ scores,
                                                 float* __restrict__ weights) {
    __shared__ float red[8];
    int b = blockIdx.x;
    int tid = threadIdx.x;
    const float* srow = scores + b * S_;
    float vals[8];
    float mx = -INFINITY;
#pragma unroll
    for (int i = 0; i < 8; ++i) {
        vals[i] = srow[tid + i * 256];
        mx = fmaxf(mx, vals[i]);
    }
    for (int off = 32; off; off >>= 1) mx = fmaxf(mx, __shfl_xor(mx, off, 64));
    int wave = tid >> 6;
    if ((tid & 63) == 0) red[wave] = mx;
    __syncthreads();
    mx = fmaxf(fmaxf(red[0], red[1]), fmaxf(red[2], red[3]));
    float sum = 0.f;
#pragma unroll
    for (int i = 0; i < 8; ++i) {
        vals[i] = expf(vals[i] - mx);
        sum += vals[i];
    }
    for (int off = 32; off; off >>= 1) sum += __shfl_xor(sum, off, 64);
    if ((tid & 63) == 0) red[4 + wave] = sum;
    __syncthreads();
    sum = red[4] + red[5] + red[6] + red[7];
    float inv = 1.f / sum;
#pragma unroll
    for (int i = 0; i < 8; ++i)
        weights[b * S_ + tid + i * 256] = vals[i] * inv;
}

// ---- Kernel 4: context partials over s-chunks (skip zero weights)
__global__ __launch_bounds__(256) void k_ctx_partial(const float* __restrict__ weights,
                                                     const float* __restrict__ enc,
                                                     float* __restrict__ part) {
    int b = blockIdx.x >> 4;       // 0..31
    int chunk = blockIdx.x & 15;   // 0..15
    int tid = threadIdx.x;
    int d0 = tid * 4;              // covers D=1024 with 256 threads * float4
    float4 acc = {0.f, 0.f, 0.f, 0.f};
    int s0 = chunk * 128;
    const float* wrow = weights + b * S_;
    for (int s = s0; s < s0 + 128; ++s) {
        float w = wrow[s];
        if (w != 0.f) {
            float4 e = *(const float4*)(enc + (size_t)(b * S_ + s) * D_ + d0);
            acc.x += w * e.x; acc.y += w * e.y; acc.z += w * e.z; acc.w += w * e.w;
        }
    }
    *(float4*)(part + (size_t)blockIdx.x * D_ + d0) = acc;
}

// ---- Kernel 5: reduce partials -> context
__global__ __launch_bounds__(256) void k_ctx_reduce(const float* __restrict__ part,
                                                    float* __restrict__ ctx) {
    int bd = blockIdx.x * 256 + threadIdx.x;  // 32768
    int b = bd >> 10, d = bd & 1023;
    float acc = 0.f;
#pragma unroll
    for (int c = 0; c < 16; ++c)
        acc += part[(size_t)(b * 16 + c) * D_ + d];
    ctx[bd] = acc;
}

extern "C" void kernel_launch(void* const* d_in, const int* in_sizes, int n_in,
                              void* d_out, int out_size, void* d_ws, size_t ws_size,
                              hipStream_t stream) {
    const float* ls   = (const float*)d_in[0];  // (32,1024)
    const float* enc  = (const float*)d_in[1];  // (32,2048,1024)
    const int*   mask = (const int*)d_in[2];    // (32,2048)
    const float* W    = (const float*)d_in[3];  // (1024,2048)
    const float* bias = (const float*)d_in[4];  // (1024,)
    const float* V    = (const float*)d_in[5];  // (1024,)

    float* out     = (float*)d_out;
    float* ctx     = out;               // 32*1024
    float* weights = out + 32768;       // 32*2048
    float* scores  = out + 98304;       // 32*2048

    float* hp   = (float*)d_ws;         // 32768 floats
    float* part = hp + 32768;           // 512*1024 floats (2 MB)

    k_hpart<<<128, 256, 0, stream>>>(ls, W, hp);
    k_scores<<<1024, 256, 0, stream>>>(enc, W, hp, bias, V, mask, scores);
    k_softmax<<<32, 256, 0, stream>>>(scores, weights);
    k_ctx_partial<<<512, 256, 0, stream>>>(weights, enc, part);
    k_ctx_reduce<<<128, 256, 0, stream>>>(part, ctx);
}

// Round 2
// 1033.868 us; speedup vs baseline: 2.3171x; 2.3171x over previous
//
#include <hip/hip_runtime.h>
#include <math.h>

#define B_ 32
#define S_ 2048
#define D_ 1024
#define H_ 1024
#define NEGV -1000000000000.0f

typedef __attribute__((ext_vector_type(8))) short bf16x8;
typedef __attribute__((ext_vector_type(4))) float f32x4;

static __device__ __forceinline__ unsigned short f2bf(float x) {
    union { float f; unsigned u; } v; v.f = x;
    unsigned r = v.u + 0x7FFF + ((v.u >> 16) & 1);
    return (unsigned short)(r >> 16);
}
static __device__ __forceinline__ float bf2f(unsigned short h) {
    union { float f; unsigned u; } v; v.u = ((unsigned)h) << 16; return v.f;
}
static __device__ __forceinline__ float tanh_fast(float x) {
    float e = __expf(2.f * x);
    return 1.f - 2.f / (e + 1.f);
}

// ---- Kernel 0: split We = W[:, D:] into bf16 hi/lo, row-major [H][D]
__global__ __launch_bounds__(256) void k_splitW(const float* __restrict__ W,
                                                unsigned short* __restrict__ hi,
                                                unsigned short* __restrict__ lo) {
    int idx = blockIdx.x * 256 + threadIdx.x;   // 131072 chunks of 8
    int h = idx >> 7, kc = idx & 127;
    const float* src = W + (size_t)h * (2 * D_) + D_ + kc * 8;
    float4 a = *(const float4*)src;
    float4 c = *(const float4*)(src + 4);
    float v[8] = {a.x, a.y, a.z, a.w, c.x, c.y, c.z, c.w};
    unsigned short th[8], tl[8];
#pragma unroll
    for (int j = 0; j < 8; ++j) {
        th[j] = f2bf(v[j]);
        tl[j] = f2bf(v[j] - bf2f(th[j]));
    }
    uint4 hw, lw;
    hw.x = th[0] | ((unsigned)th[1] << 16); hw.y = th[2] | ((unsigned)th[3] << 16);
    hw.z = th[4] | ((unsigned)th[5] << 16); hw.w = th[6] | ((unsigned)th[7] << 16);
    lw.x = tl[0] | ((unsigned)tl[1] << 16); lw.y = tl[2] | ((unsigned)tl[3] << 16);
    lw.z = tl[4] | ((unsigned)tl[5] << 16); lw.w = tl[6] | ((unsigned)tl[7] << 16);
    *(uint4*)(hi + (size_t)h * D_ + kc * 8) = hw;
    *(uint4*)(lo + (size_t)h * D_ + kc * 8) = lw;
}

// ---- Kernel 1: h_part[b,h] = sum_d ls[b,d] * W[h, d]  (fp32, tiny)
__global__ __launch_bounds__(256) void k_hpart(const float* __restrict__ ls,
                                               const float* __restrict__ W,
                                               float* __restrict__ hp) {
    int bh = blockIdx.x * 256 + threadIdx.x;
    int b = bh >> 10, h = bh & 1023;
    const float* lsr = ls + b * D_;
    const float* wr  = W + (size_t)h * (2 * D_);
    float acc = 0.f;
#pragma unroll 4
    for (int d = 0; d < D_; d += 4) {
        float4 a = *(const float4*)(lsr + d);
        float4 w = *(const float4*)(wr + d);
        acc += a.x * w.x + a.y * w.y + a.z * w.z + a.w * w.w;
    }
    hp[bh] = acc;
}

// ---- Kernel 2: fused scores via split-bf16 MFMA
// tile: M=128 (rows of b*S+s), N=128 (h), BK=64; 4 waves, each 64x64 (4x4 frags)
__global__ __launch_bounds__(256, 2) void k_scores_mfma(
    const float* __restrict__ enc,
    const unsigned short* __restrict__ Whi,
    const unsigned short* __restrict__ Wlo,
    const float* __restrict__ hp,
    const float* __restrict__ bias,
    const float* __restrict__ V,
    const int* __restrict__ mask,
    float* __restrict__ scores_out)
{
    __shared__ __align__(16) unsigned short smem[4 * 8192];  // 64 KB
    unsigned short* sAhi = smem;
    unsigned short* sAlo = smem + 8192;
    unsigned short* sBhi = smem + 16384;
    unsigned short* sBlo = smem + 24576;

    const int tid  = threadIdx.x;
    const int lane = tid & 63, wid = tid >> 6;
    const int wr = wid >> 1, wc = wid & 1;
    const int l15 = lane & 15, lhi = lane >> 4;
    const int m0 = blockIdx.x * 128;
    const int b  = m0 >> 11;                 // 128 | 2048, tiles never straddle b

    float rowsum[4][4] = {};

    // staging registers (prefetched one (nb,kb) step ahead)
    float4 pa[8];       // A: 4 chunks x 8 fp32
    uint4  pbh[4], pbl[4];

#define STAGE_LOAD(NB, KB) do {                                            \
    _Pragma("unroll")                                                      \
    for (int i_ = 0; i_ < 4; ++i_) {                                       \
        int c_ = tid + i_ * 256;                                           \
        int r_ = c_ >> 3, kc_ = c_ & 7;                                    \
        const float* ap_ = enc + (size_t)(m0 + r_) * D_ + (KB) * 64 + kc_ * 8; \
        pa[2 * i_]     = *(const float4*)ap_;                              \
        pa[2 * i_ + 1] = *(const float4*)(ap_ + 4);                        \
        size_t bo_ = (size_t)((NB) * 128 + r_) * D_ + (KB) * 64 + kc_ * 8; \
        pbh[i_] = *(const uint4*)(Whi + bo_);                              \
        pbl[i_] = *(const uint4*)(Wlo + bo_);                              \
    }                                                                      \
} while (0)

#define STAGE_WRITE() do {                                                 \
    _Pragma("unroll")                                                      \
    for (int i_ = 0; i_ < 4; ++i_) {                                       \
        int c_ = tid + i_ * 256;                                           \
        int sc_ = c_ ^ ((c_ >> 3) & 7);                                    \
        float vv_[8] = {pa[2*i_].x, pa[2*i_].y, pa[2*i_].z, pa[2*i_].w,    \
                        pa[2*i_+1].x, pa[2*i_+1].y, pa[2*i_+1].z, pa[2*i_+1].w}; \
        unsigned short th_[8], tl_[8];                                     \
        _Pragma("unroll")                                                  \
        for (int j_ = 0; j_ < 8; ++j_) {                                   \
            th_[j_] = f2bf(vv_[j_]);                                       \
            tl_[j_] = f2bf(vv_[j_] - bf2f(th_[j_]));                       \
        }                                                                  \
        uint4 hw_, lw_;                                                    \
        hw_.x = th_[0] | ((unsigned)th_[1] << 16); hw_.y = th_[2] | ((unsigned)th_[3] << 16); \
        hw_.z = th_[4] | ((unsigned)th_[5] << 16); hw_.w = th_[6] | ((unsigned)th_[7] << 16); \
        lw_.x = tl_[0] | ((unsigned)tl_[1] << 16); lw_.y = tl_[2] | ((unsigned)tl_[3] << 16); \
        lw_.z = tl_[4] | ((unsigned)tl_[5] << 16); lw_.w = tl_[6] | ((unsigned)tl_[7] << 16); \
        *(uint4*)&sAhi[sc_ * 8] = hw_;                                     \
        *(uint4*)&sAlo[sc_ * 8] = lw_;                                     \
        *(uint4*)&sBhi[sc_ * 8] = pbh[i_];                                 \
        *(uint4*)&sBlo[sc_ * 8] = pbl[i_];                                 \
    }                                                                      \
} while (0)

    STAGE_LOAD(0, 0);

    for (int nb = 0; nb < 8; ++nb) {
        f32x4 acc[4][4];
#pragma unroll
        for (int i = 0; i < 4; ++i)
#pragma unroll
            for (int j = 0; j < 4; ++j)
                acc[i][j] = (f32x4){0.f, 0.f, 0.f, 0.f};

        for (int kb = 0; kb < 16; ++kb) {
            __syncthreads();             // previous tile's LDS reads done
            STAGE_WRITE();
            __syncthreads();             // tile visible
            // prefetch next (nb,kb)
            int nkb = kb + 1, nnb = nb;
            if (nkb == 16) { nkb = 0; nnb = nb + 1; }
            if (nnb < 8) STAGE_LOAD(nnb, nkb);

#pragma unroll
            for (int ks = 0; ks < 2; ++ks) {
                bf16x8 bh[4], bl[4];
#pragma unroll
                for (int fn = 0; fn < 4; ++fn) {
                    int rB = wc * 64 + fn * 16 + l15;
                    int ch = (rB * 8 + ks * 4 + lhi) ^ (rB & 7);
                    bh[fn] = *(const bf16x8*)&sBhi[ch * 8];
                    bl[fn] = *(const bf16x8*)&sBlo[ch * 8];
                }
#pragma unroll
                for (int fm = 0; fm < 4; ++fm) {
                    int rA = wr * 64 + fm * 16 + l15;
                    int ch = (rA * 8 + ks * 4 + lhi) ^ (rA & 7);
                    bf16x8 ah = *(const bf16x8*)&sAhi[ch * 8];
                    bf16x8 al = *(const bf16x8*)&sAlo[ch * 8];
#pragma unroll
                    for (int fn = 0; fn < 4; ++fn) {
                        acc[fm][fn] = __builtin_amdgcn_mfma_f32_16x16x32_bf16(ah, bh[fn], acc[fm][fn], 0, 0, 0);
                        acc[fm][fn] = __builtin_amdgcn_mfma_f32_16x16x32_bf16(ah, bl[fn], acc[fm][fn], 0, 0, 0);
                        acc[fm][fn] = __builtin_amdgcn_mfma_f32_16x16x32_bf16(al, bh[fn], acc[fm][fn], 0, 0, 0);
                    }
                }
            }
        }

        // epilogue: tanh + V-weighted accumulate (registers only)
        int n0 = nb * 128;
#pragma unroll
        for (int fn = 0; fn < 4; ++fn) {
            int n = n0 + wc * 64 + fn * 16 + l15;
            float hb = hp[b * H_ + n] + bias[n];
            float vv = V[n];
#pragma unroll
            for (int fm = 0; fm < 4; ++fm) {
                f32x4 a = acc[fm][fn];
#pragma unroll
                for (int rg = 0; rg < 4; ++rg)
                    rowsum[fm][rg] += tanh_fast(a[rg] + hb) * vv;
            }
        }
    }

    // reduce across the 16 col-lanes, then across the 2 wc waves via LDS
    __syncthreads();                     // all LDS tile reads complete
    float* s_red = (float*)smem;         // 256 floats
#pragma unroll
    for (int fm = 0; fm < 4; ++fm)
#pragma unroll
        for (int rg = 0; rg < 4; ++rg) {
            float v = rowsum[fm][rg];
            v += __shfl_xor(v, 1, 16);
            v += __shfl_xor(v, 2, 16);
            v += __shfl_xor(v, 4, 16);
            v += __shfl_xor(v, 8, 16);
            if (l15 == 0)
                s_red[wc * 128 + wr * 64 + fm * 16 + lhi * 4 + rg] = v;
        }
    __syncthreads();
    if (tid < 128) {
        int m = m0 + tid;
        float sc = s_red[tid] + s_red[128 + tid];
        scores_out[m] = (mask[m] == 1) ? sc : NEGV;
    }
#undef STAGE_LOAD
#undef STAGE_WRITE
}

// ---- Kernel 3: softmax over S per batch
__global__ __launch_bounds__(256) void k_softmax(const float* __restrict__ scores,
                                                 float* __restrict__ weights) {
    __shared__ float red[8];
    int b = blockIdx.x;
    int tid = threadIdx.x;
    const float* srow = scores + b * S_;
    float vals[8];
    float mx = -INFINITY;
#pragma unroll
    for (int i = 0; i < 8; ++i) {
        vals[i] = srow[tid + i * 256];
        mx = fmaxf(mx, vals[i]);
    }
    for (int off = 32; off; off >>= 1) mx = fmaxf(mx, __shfl_xor(mx, off, 64));
    int wave = tid >> 6;
    if ((tid & 63) == 0) red[wave] = mx;
    __syncthreads();
    mx = fmaxf(fmaxf(red[0], red[1]), fmaxf(red[2], red[3]));
    float sum = 0.f;
#pragma unroll
    for (int i = 0; i < 8; ++i) {
        vals[i] = expf(vals[i] - mx);
        sum += vals[i];
    }
    for (int off = 32; off; off >>= 1) sum += __shfl_xor(sum, off, 64);
    if ((tid & 63) == 0) red[4 + wave] = sum;
    __syncthreads();
    sum = red[4] + red[5] + red[6] + red[7];
    float inv = 1.f / sum;
#pragma unroll
    for (int i = 0; i < 8; ++i)
        weights[b * S_ + tid + i * 256] = vals[i] * inv;
}

// ---- Kernel 4: context partials over s-chunks (skip zero weights)
__global__ __launch_bounds__(256) void k_ctx_partial(const float* __restrict__ weights,
                                                     const float* __restrict__ enc,
                                                     float* __restrict__ part) {
    int b = blockIdx.x >> 4;
    int chunk = blockIdx.x & 15;
    int tid = threadIdx.x;
    int d0 = tid * 4;
    float4 acc = {0.f, 0.f, 0.f, 0.f};
    int s0 = chunk * 128;
    const float* wrow = weights + b * S_;
    for (int s = s0; s < s0 + 128; ++s) {
        float w = wrow[s];
        if (w != 0.f) {
            float4 e = *(const float4*)(enc + (size_t)(b * S_ + s) * D_ + d0);
            acc.x += w * e.x; acc.y += w * e.y; acc.z += w * e.z; acc.w += w * e.w;
        }
    }
    *(float4*)(part + (size_t)blockIdx.x * D_ + d0) = acc;
}

// ---- Kernel 5: reduce partials -> context
__global__ __launch_bounds__(256) void k_ctx_reduce(const float* __restrict__ part,
                                                    float* __restrict__ ctx) {
    int bd = blockIdx.x * 256 + threadIdx.x;
    int b = bd >> 10, d = bd & 1023;
    float acc = 0.f;
#pragma unroll
    for (int c = 0; c < 16; ++c)
        acc += part[(size_t)(b * 16 + c) * D_ + d];
    ctx[bd] = acc;
}

extern "C" void kernel_launch(void* const* d_in, const int* in_sizes, int n_in,
                              void* d_out, int out_size, void* d_ws, size_t ws_size,
                              hipStream_t stream) {
    const float* ls   = (const float*)d_in[0];
    const float* enc  = (const float*)d_in[1];
    const int*   mask = (const int*)d_in[2];
    const float* W    = (const float*)d_in[3];
    const float* bias = (const float*)d_in[4];
    const float* V    = (const float*)d_in[5];

    float* out     = (float*)d_out;
    float* ctx     = out;
    float* weights = out + 32768;
    float* scores  = out + 98304;

    unsigned short* Whi = (unsigned short*)d_ws;     // 1 Mi elements
    unsigned short* Wlo = Whi + 1048576;             // 1 Mi elements
    float* hp   = (float*)(Wlo + 1048576);           // 32768 floats
    float* part = hp + 32768;                        // 524288 floats

    k_splitW<<<512, 256, 0, stream>>>(W, Whi, Wlo);
    k_hpart<<<128, 256, 0, stream>>>(ls, W, hp);
    k_scores_mfma<<<512, 256, 0, stream>>>(enc, Whi, Wlo, hp, bias, V, mask, scores);
    k_softmax<<<32, 256, 0, stream>>>(scores, weights);
    k_ctx_partial<<<512, 256, 0, stream>>>(weights, enc, part);
    k_ctx_reduce<<<128, 256, 0, stream>>>(part, ctx);
}

// Round 4
// 608.241 us; speedup vs baseline: 3.9385x; 1.6998x over previous
//
#include <hip/hip_runtime.h>
#include <math.h>
#include <stdint.h>

#define B_ 32
#define S_ 2048
#define D_ 1024
#define H_ 1024
#define NEGV -1000000000000.0f

typedef __attribute__((ext_vector_type(8))) short bf16x8;
typedef __attribute__((ext_vector_type(4))) float f32x4;

static __device__ __forceinline__ unsigned short f2bf(float x) {
    union { float f; unsigned u; } v; v.f = x;
    unsigned r = v.u + 0x7FFF + ((v.u >> 16) & 1);
    return (unsigned short)(r >> 16);
}
static __device__ __forceinline__ float bf2f(unsigned short h) {
    union { float f; unsigned u; } v; v.u = ((unsigned)h) << 16; return v.f;
}
static __device__ __forceinline__ float tanh_fast(float x) {
    float e = __expf(2.f * x);
    return 1.f - 2.f / (e + 1.f);
}
static __device__ __forceinline__ void gl_lds16(unsigned short* lds, const unsigned short* g) {
    __builtin_amdgcn_global_load_lds(
        (const __attribute__((address_space(1))) unsigned int*)(const void*)g,
        (__attribute__((address_space(3))) unsigned int*)(void*)lds,
        16, 0, 0);
}

// ---- split We = W[:, D:] into bf16 hi/lo, row-major [H][D]
__global__ __launch_bounds__(256) void k_splitW(const float* __restrict__ W,
                                                unsigned short* __restrict__ hi,
                                                unsigned short* __restrict__ lo) {
    int idx = blockIdx.x * 256 + threadIdx.x;
    int h = idx >> 7, kc = idx & 127;
    const float* src = W + (size_t)h * (2 * D_) + D_ + kc * 8;
    float4 a = *(const float4*)src;
    float4 c = *(const float4*)(src + 4);
    float v[8] = {a.x, a.y, a.z, a.w, c.x, c.y, c.z, c.w};
    unsigned short th[8], tl[8];
#pragma unroll
    for (int j = 0; j < 8; ++j) {
        th[j] = f2bf(v[j]);
        tl[j] = f2bf(v[j] - bf2f(th[j]));
    }
    uint4 hw, lw;
    hw.x = th[0] | ((unsigned)th[1] << 16); hw.y = th[2] | ((unsigned)th[3] << 16);
    hw.z = th[4] | ((unsigned)th[5] << 16); hw.w = th[6] | ((unsigned)th[7] << 16);
    lw.x = tl[0] | ((unsigned)tl[1] << 16); lw.y = tl[2] | ((unsigned)tl[3] << 16);
    lw.z = tl[4] | ((unsigned)tl[5] << 16); lw.w = tl[6] | ((unsigned)tl[7] << 16);
    *(uint4*)(hi + (size_t)h * D_ + kc * 8) = hw;
    *(uint4*)(lo + (size_t)h * D_ + kc * 8) = lw;
}

// ---- split enc into bf16 hi/lo (flat 64M elements)
__global__ __launch_bounds__(256) void k_split_enc(const float* __restrict__ enc,
                                                   unsigned short* __restrict__ hi,
                                                   unsigned short* __restrict__ lo) {
    size_t base = ((size_t)blockIdx.x * 256 + threadIdx.x) * 8;
    float4 a = *(const float4*)(enc + base);
    float4 c = *(const float4*)(enc + base + 4);
    float v[8] = {a.x, a.y, a.z, a.w, c.x, c.y, c.z, c.w};
    unsigned short th[8], tl[8];
#pragma unroll
    for (int j = 0; j < 8; ++j) {
        th[j] = f2bf(v[j]);
        tl[j] = f2bf(v[j] - bf2f(th[j]));
    }
    uint4 hw, lw;
    hw.x = th[0] | ((unsigned)th[1] << 16); hw.y = th[2] | ((unsigned)th[3] << 16);
    hw.z = th[4] | ((unsigned)th[5] << 16); hw.w = th[6] | ((unsigned)th[7] << 16);
    lw.x = tl[0] | ((unsigned)tl[1] << 16); lw.y = tl[2] | ((unsigned)tl[3] << 16);
    lw.z = tl[4] | ((unsigned)tl[5] << 16); lw.w = tl[6] | ((unsigned)tl[7] << 16);
    *(uint4*)(hi + base) = hw;
    *(uint4*)(lo + base) = lw;
}

// ---- h_part[b,h] = sum_d ls[b,d] * W[h,d]
__global__ __launch_bounds__(256) void k_hpart(const float* __restrict__ ls,
                                               const float* __restrict__ W,
                                               float* __restrict__ hp) {
    int bh = blockIdx.x * 256 + threadIdx.x;
    int b = bh >> 10, h = bh & 1023;
    const float* lsr = ls + b * D_;
    const float* wr  = W + (size_t)h * (2 * D_);
    float acc = 0.f;
#pragma unroll 4
    for (int d = 0; d < D_; d += 4) {
        float4 a = *(const float4*)(lsr + d);
        float4 w = *(const float4*)(wr + d);
        acc += a.x * w.x + a.y * w.y + a.z * w.z + a.w * w.w;
    }
    hp[bh] = acc;
}

// ---- main GEMM: m97 structure, pure bf16, global_load_lds staging.
// grid 4096 = 512 m-tiles x 8 nb; XCD-mapped: xcd=bid&7, mt=xcd*64+(idx>>3), nb=idx&7
// writes per-nb row partials to spart[nb][65536]
__global__ __launch_bounds__(256) void k_scores_mfma2(
    const unsigned short* __restrict__ Ahi, const unsigned short* __restrict__ Alo,
    const unsigned short* __restrict__ Bhi, const unsigned short* __restrict__ Blo,
    const float* __restrict__ hp, const float* __restrict__ bias,
    const float* __restrict__ V, float* __restrict__ spart)
{
    __shared__ __align__(16) unsigned short smem[4 * 8192];  // 64 KB
    unsigned short* sAhi = smem;
    unsigned short* sAlo = smem + 8192;
    unsigned short* sBhi = smem + 16384;
    unsigned short* sBlo = smem + 24576;

    const int tid = threadIdx.x;
    const int lane = tid & 63, wid = tid >> 6;
    const int wr = wid >> 1, wc = wid & 1;
    const int l15 = lane & 15, lhi = lane >> 4;

    const int bid = blockIdx.x;
    const int xcd = bid & 7, idx = bid >> 3;
    const int mt = xcd * 64 + (idx >> 3);
    const int nb = idx & 7;
    const int m0 = mt * 128;
    const int b  = m0 >> 11;

    // staging geometry: wave w covers rows [w*32, w*32+32), 4 issues of 8 rows
    const int srow = wid * 32 + (lane >> 3);
    const int scol = (lane & 7) * 8;
    const size_t a_base = (size_t)(m0 + srow) * D_ + scol;
    const size_t b_base = (size_t)(nb * 128 + srow) * D_ + scol;

    f32x4 acc[4][4];
#pragma unroll
    for (int i = 0; i < 4; ++i)
#pragma unroll
        for (int j = 0; j < 4; ++j)
            acc[i][j] = (f32x4){0.f, 0.f, 0.f, 0.f};

    for (int kb = 0; kb < 16; ++kb) {
        const int ko = kb * 64;
#pragma unroll
        for (int j = 0; j < 4; ++j) {
            const int lofs = (wid * 32 + j * 8) * 64;
            const size_t go = (size_t)j * 8 * D_ + ko;
            gl_lds16(&sAhi[lofs], Ahi + a_base + go);
            gl_lds16(&sAlo[lofs], Alo + a_base + go);
            gl_lds16(&sBhi[lofs], Bhi + b_base + go);
            gl_lds16(&sBlo[lofs], Blo + b_base + go);
        }
        __syncthreads();   // vmcnt drained by compiler -> tile visible
#pragma unroll
        for (int ks = 0; ks < 2; ++ks) {
            bf16x8 bh[4], bl[4];
#pragma unroll
            for (int fn = 0; fn < 4; ++fn) {
                int o = (wc * 64 + fn * 16 + l15) * 64 + ks * 32 + lhi * 8;
                bh[fn] = *(const bf16x8*)&sBhi[o];
                bl[fn] = *(const bf16x8*)&sBlo[o];
            }
#pragma unroll
            for (int fm = 0; fm < 4; ++fm) {
                int o = (wr * 64 + fm * 16 + l15) * 64 + ks * 32 + lhi * 8;
                bf16x8 a_h = *(const bf16x8*)&sAhi[o];
                bf16x8 a_l = *(const bf16x8*)&sAlo[o];
#pragma unroll
                for (int fn = 0; fn < 4; ++fn) {
                    acc[fm][fn] = __builtin_amdgcn_mfma_f32_16x16x32_bf16(a_h, bh[fn], acc[fm][fn], 0, 0, 0);
                    acc[fm][fn] = __builtin_amdgcn_mfma_f32_16x16x32_bf16(a_h, bl[fn], acc[fm][fn], 0, 0, 0);
                    acc[fm][fn] = __builtin_amdgcn_mfma_f32_16x16x32_bf16(a_l, bh[fn], acc[fm][fn], 0, 0, 0);
                }
            }
        }
        __syncthreads();   // reads done before next stage overwrites
    }

    // epilogue: tanh + V-weighted column reduce (this block's 128 cols)
    float rowsum[4][4] = {};
#pragma unroll
    for (int fn = 0; fn < 4; ++fn) {
        int n = nb * 128 + wc * 64 + fn * 16 + l15;
        float hb = hp[b * H_ + n] + bias[n];
        float vv = V[n];
#pragma unroll
        for (int fm = 0; fm < 4; ++fm) {
            f32x4 a = acc[fm][fn];
#pragma unroll
            for (int rg = 0; rg < 4; ++rg)
                rowsum[fm][rg] += tanh_fast(a[rg] + hb) * vv;
        }
    }
    float* s_red = (float*)smem;
#pragma unroll
    for (int fm = 0; fm < 4; ++fm)
#pragma unroll
        for (int rg = 0; rg < 4; ++rg) {
            float v = rowsum[fm][rg];
            v += __shfl_xor(v, 1, 16);
            v += __shfl_xor(v, 2, 16);
            v += __shfl_xor(v, 4, 16);
            v += __shfl_xor(v, 8, 16);
            if (l15 == 0)
                s_red[wc * 128 + wr * 64 + fm * 16 + lhi * 4 + rg] = v;
        }
    __syncthreads();
    if (tid < 128)
        spart[((size_t)nb << 16) + m0 + tid] = s_red[tid] + s_red[128 + tid];
}

// ---- fold nb-partials + mask + softmax
__global__ __launch_bounds__(256) void k_softmax_fold(const float* __restrict__ spart,
                                                      const int* __restrict__ mask,
                                                      float* __restrict__ scores_out,
                                                      float* __restrict__ weights) {
    __shared__ float red[8];
    int b = blockIdx.x, tid = threadIdx.x;
    float vals[8];
    float mx = -INFINITY;
#pragma unroll
    for (int i = 0; i < 8; ++i) {
        int m = b * S_ + tid + i * 256;
        float s = 0.f;
#pragma unroll
        for (int nb = 0; nb < 8; ++nb)
            s += spart[((size_t)nb << 16) + m];
        s = (mask[m] == 1) ? s : NEGV;
        scores_out[m] = s;
        vals[i] = s;
        mx = fmaxf(mx, s);
    }
    for (int off = 32; off; off >>= 1) mx = fmaxf(mx, __shfl_xor(mx, off, 64));
    int wave = tid >> 6;
    if ((tid & 63) == 0) red[wave] = mx;
    __syncthreads();
    mx = fmaxf(fmaxf(red[0], red[1]), fmaxf(red[2], red[3]));
    float sum = 0.f;
#pragma unroll
    for (int i = 0; i < 8; ++i) {
        vals[i] = expf(vals[i] - mx);
        sum += vals[i];
    }
    for (int off = 32; off; off >>= 1) sum += __shfl_xor(sum, off, 64);
    if ((tid & 63) == 0) red[4 + wave] = sum;
    __syncthreads();
    sum = red[4] + red[5] + red[6] + red[7];
    float inv = 1.f / sum;
#pragma unroll
    for (int i = 0; i < 8; ++i)
        weights[b * S_ + tid + i * 256] = vals[i] * inv;
}

// ---- context partials (skip zero weights)
__global__ __launch_bounds__(256) void k_ctx_partial(const float* __restrict__ weights,
                                                     const float* __restrict__ enc,
                                                     float* __restrict__ part) {
    int b = blockIdx.x >> 4;
    int chunk = blockIdx.x & 15;
    int tid = threadIdx.x;
    int d0 = tid * 4;
    float4 acc = {0.f, 0.f, 0.f, 0.f};
    int s0 = chunk * 128;
    const float* wrow = weights + b * S_;
    for (int s = s0; s < s0 + 128; ++s) {
        float w = wrow[s];
        if (w != 0.f) {
            float4 e = *(const float4*)(enc + (size_t)(b * S_ + s) * D_ + d0);
            acc.x += w * e.x; acc.y += w * e.y; acc.z += w * e.z; acc.w += w * e.w;
        }
    }
    *(float4*)(part + (size_t)blockIdx.x * D_ + d0) = acc;
}

__global__ __launch_bounds__(256) void k_ctx_reduce(const float* __restrict__ part,
                                                    float* __restrict__ ctx) {
    int bd = blockIdx.x * 256 + threadIdx.x;
    int b = bd >> 10, d = bd & 1023;
    float acc = 0.f;
#pragma unroll
    for (int c = 0; c < 16; ++c)
        acc += part[(size_t)(b * 16 + c) * D_ + d];
    ctx[bd] = acc;
}

// ================== fallback (round-2) scores kernel, used if ws too small ==================
__global__ __launch_bounds__(256, 2) void k_scores_mfma_fb(
    const float* __restrict__ enc,
    const unsigned short* __restrict__ Whi,
    const unsigned short* __restrict__ Wlo,
    const float* __restrict__ hp,
    const float* __restrict__ bias,
    const float* __restrict__ V,
    const int* __restrict__ mask,
    float* __restrict__ scores_out)
{
    __shared__ __align__(16) unsigned short smem[4 * 8192];
    unsigned short* sAhi = smem;
    unsigned short* sAlo = smem + 8192;
    unsigned short* sBhi = smem + 16384;
    unsigned short* sBlo = smem + 24576;

    const int tid  = threadIdx.x;
    const int lane = tid & 63, wid = tid >> 6;
    const int wr = wid >> 1, wc = wid & 1;
    const int l15 = lane & 15, lhi = lane >> 4;
    const int m0 = blockIdx.x * 128;
    const int b  = m0 >> 11;

    float rowsum[4][4] = {};
    float4 pa[8];
    uint4  pbh[4], pbl[4];

#define STAGE_LOAD(NB, KB) do {                                            \
    _Pragma("unroll")                                                      \
    for (int i_ = 0; i_ < 4; ++i_) {                                       \
        int c_ = tid + i_ * 256;                                           \
        int r_ = c_ >> 3, kc_ = c_ & 7;                                    \
        const float* ap_ = enc + (size_t)(m0 + r_) * D_ + (KB) * 64 + kc_ * 8; \
        pa[2 * i_]     = *(const float4*)ap_;                              \
        pa[2 * i_ + 1] = *(const float4*)(ap_ + 4);                        \
        size_t bo_ = (size_t)((NB) * 128 + r_) * D_ + (KB) * 64 + kc_ * 8; \
        pbh[i_] = *(const uint4*)(Whi + bo_);                              \
        pbl[i_] = *(const uint4*)(Wlo + bo_);                              \
    }                                                                      \
} while (0)

#define STAGE_WRITE() do {                                                 \
    _Pragma("unroll")                                                      \
    for (int i_ = 0; i_ < 4; ++i_) {                                       \
        int c_ = tid + i_ * 256;                                           \
        int sc_ = c_ ^ ((c_ >> 3) & 7);                                    \
        float vv_[8] = {pa[2*i_].x, pa[2*i_].y, pa[2*i_].z, pa[2*i_].w,    \
                        pa[2*i_+1].x, pa[2*i_+1].y, pa[2*i_+1].z, pa[2*i_+1].w}; \
        unsigned short th_[8], tl_[8];                                     \
        _Pragma("unroll")                                                  \
        for (int j_ = 0; j_ < 8; ++j_) {                                   \
            th_[j_] = f2bf(vv_[j_]);                                       \
            tl_[j_] = f2bf(vv_[j_] - bf2f(th_[j_]));                       \
        }                                                                  \
        uint4 hw_, lw_;                                                    \
        hw_.x = th_[0] | ((unsigned)th_[1] << 16); hw_.y = th_[2] | ((unsigned)th_[3] << 16); \
        hw_.z = th_[4] | ((unsigned)th_[5] << 16); hw_.w = th_[6] | ((unsigned)th_[7] << 16); \
        lw_.x = tl_[0] | ((unsigned)tl_[1] << 16); lw_.y = tl_[2] | ((unsigned)tl_[3] << 16); \
        lw_.z = tl_[4] | ((unsigned)tl_[5] << 16); lw_.w = tl_[6] | ((unsigned)tl_[7] << 16); \
        *(uint4*)&sAhi[sc_ * 8] = hw_;                                     \
        *(uint4*)&sAlo[sc_ * 8] = lw_;                                     \
        *(uint4*)&sBhi[sc_ * 8] = pbh[i_];                                 \
        *(uint4*)&sBlo[sc_ * 8] = pbl[i_];                                 \
    }                                                                      \
} while (0)

    STAGE_LOAD(0, 0);

    for (int nb = 0; nb < 8; ++nb) {
        f32x4 acc[4][4];
#pragma unroll
        for (int i = 0; i < 4; ++i)
#pragma unroll
            for (int j = 0; j < 4; ++j)
                acc[i][j] = (f32x4){0.f, 0.f, 0.f, 0.f};

        for (int kb = 0; kb < 16; ++kb) {
            __syncthreads();
            STAGE_WRITE();
            __syncthreads();
            int nkb = kb + 1, nnb = nb;
            if (nkb == 16) { nkb = 0; nnb = nb + 1; }
            if (nnb < 8) STAGE_LOAD(nnb, nkb);

#pragma unroll
            for (int ks = 0; ks < 2; ++ks) {
                bf16x8 bh[4], bl[4];
#pragma unroll
                for (int fn = 0; fn < 4; ++fn) {
                    int rB = wc * 64 + fn * 16 + l15;
                    int ch = (rB * 8 + ks * 4 + lhi) ^ (rB & 7);
                    bh[fn] = *(const bf16x8*)&sBhi[ch * 8];
                    bl[fn] = *(const bf16x8*)&sBlo[ch * 8];
                }
#pragma unroll
                for (int fm = 0; fm < 4; ++fm) {
                    int rA = wr * 64 + fm * 16 + l15;
                    int ch = (rA * 8 + ks * 4 + lhi) ^ (rA & 7);
                    bf16x8 ah = *(const bf16x8*)&sAhi[ch * 8];
                    bf16x8 al = *(const bf16x8*)&sAlo[ch * 8];
#pragma unroll
                    for (int fn = 0; fn < 4; ++fn) {
                        acc[fm][fn] = __builtin_amdgcn_mfma_f32_16x16x32_bf16(ah, bh[fn], acc[fm][fn], 0, 0, 0);
                        acc[fm][fn] = __builtin_amdgcn_mfma_f32_16x16x32_bf16(ah, bl[fn], acc[fm][fn], 0, 0, 0);
                        acc[fm][fn] = __builtin_amdgcn_mfma_f32_16x16x32_bf16(al, bh[fn], acc[fm][fn], 0, 0, 0);
                    }
                }
            }
        }

        int n0 = nb * 128;
#pragma unroll
        for (int fn = 0; fn < 4; ++fn) {
            int n = n0 + wc * 64 + fn * 16 + l15;
            float hb = hp[b * H_ + n] + bias[n];
            float vv = V[n];
#pragma unroll
            for (int fm = 0; fm < 4; ++fm) {
                f32x4 a = acc[fm][fn];
#pragma unroll
                for (int rg = 0; rg < 4; ++rg)
                    rowsum[fm][rg] += tanh_fast(a[rg] + hb) * vv;
            }
        }
    }

    __syncthreads();
    float* s_red = (float*)smem;
#pragma unroll
    for (int fm = 0; fm < 4; ++fm)
#pragma unroll
        for (int rg = 0; rg < 4; ++rg) {
            float v = rowsum[fm][rg];
            v += __shfl_xor(v, 1, 16);
            v += __shfl_xor(v, 2, 16);
            v += __shfl_xor(v, 4, 16);
            v += __shfl_xor(v, 8, 16);
            if (l15 == 0)
                s_red[wc * 128 + wr * 64 + fm * 16 + lhi * 4 + rg] = v;
        }
    __syncthreads();
    if (tid < 128) {
        int m = m0 + tid;
        float sc = s_red[tid] + s_red[128 + tid];
        scores_out[m] = (mask[m] == 1) ? sc : NEGV;
    }
#undef STAGE_LOAD
#undef STAGE_WRITE
}

__global__ __launch_bounds__(256) void k_softmax(const float* __restrict__ scores,
                                                 float* __restrict__ weights) {
    __shared__ float red[8];
    int b = blockIdx.x;
    int tid = threadIdx.x;
    const float* srow = scores + b * S_;
    float vals[8];
    float mx = -INFINITY;
#pragma unroll
    for (int i = 0; i < 8; ++i) {
        vals[i] = srow[tid + i * 256];
        mx = fmaxf(mx, vals[i]);
    }
    for (int off = 32; off; off >>= 1) mx = fmaxf(mx, __shfl_xor(mx, off, 64));
    int wave = tid >> 6;
    if ((tid & 63) == 0) red[wave] = mx;
    __syncthreads();
    mx = fmaxf(fmaxf(red[0], red[1]), fmaxf(red[2], red[3]));
    float sum = 0.f;
#pragma unroll
    for (int i = 0; i < 8; ++i) {
        vals[i] = expf(vals[i] - mx);
        sum += vals[i];
    }
    for (int off = 32; off; off >>= 1) sum += __shfl_xor(sum, off, 64);
    if ((tid & 63) == 0) red[4 + wave] = sum;
    __syncthreads();
    sum = red[4] + red[5] + red[6] + red[7];
    float inv = 1.f / sum;
#pragma unroll
    for (int i = 0; i < 8; ++i)
        weights[b * S_ + tid + i * 256] = vals[i] * inv;
}

extern "C" void kernel_launch(void* const* d_in, const int* in_sizes, int n_in,
                              void* d_out, int out_size, void* d_ws, size_t ws_size,
                              hipStream_t stream) {
    const float* ls   = (const float*)d_in[0];
    const float* enc  = (const float*)d_in[1];
    const int*   mask = (const int*)d_in[2];
    const float* W    = (const float*)d_in[3];
    const float* bias = (const float*)d_in[4];
    const float* V    = (const float*)d_in[5];

    float* out     = (float*)d_out;
    float* ctx     = out;
    float* weights = out + 32768;
    float* scores  = out + 98304;

    // exact fast-path workspace need:
    // ench+encl (2*134217728) + Whi+Wlo (2*2097152) + hp (131072)
    // + spart (2097152) + part (2097152) = 276955136 bytes
    const size_t need = 276955136ull;

    if (ws_size >= need) {
        unsigned short* ench = (unsigned short*)d_ws;        // 64Mi shorts = 128 MB
        unsigned short* encl = ench + 67108864;              // 128 MB
        unsigned short* Whi  = encl + 67108864;              // 2 MB
        unsigned short* Wlo  = Whi + 1048576;                // 2 MB
        float* hp    = (float*)(Wlo + 1048576);              // 128 KB
        float* spart = hp + 32768;                           // 2 MB
        float* part  = spart + 524288;                       // 2 MB

        k_splitW<<<512, 256, 0, stream>>>(W, Whi, Wlo);
        k_split_enc<<<32768, 256, 0, stream>>>(enc, ench, encl);
        k_hpart<<<128, 256, 0, stream>>>(ls, W, hp);
        k_scores_mfma2<<<4096, 256, 0, stream>>>(ench, encl, Whi, Wlo, hp, bias, V, spart);
        k_softmax_fold<<<32, 256, 0, stream>>>(spart, mask, scores, weights);
        k_ctx_partial<<<512, 256, 0, stream>>>(weights, enc, part);
        k_ctx_reduce<<<128, 256, 0, stream>>>(part, ctx);
    } else {
        unsigned short* Whi = (unsigned short*)d_ws;
        unsigned short* Wlo = Whi + 1048576;
        float* hp   = (float*)(Wlo + 1048576);
        float* part = hp + 32768;

        k_splitW<<<512, 256, 0, stream>>>(W, Whi, Wlo);
        k_hpart<<<128, 256, 0, stream>>>(ls, W, hp);
        k_scores_mfma_fb<<<512, 256, 0, stream>>>(enc, Whi, Wlo, hp, bias, V, mask, scores);
        k_softmax<<<32, 256, 0, stream>>>(scores, weights);
        k_ctx_partial<<<512, 256, 0, stream>>>(weights, enc, part);
        k_ctx_reduce<<<128, 256, 0, stream>>>(part, ctx);
    }
}

// Round 5
// 534.310 us; speedup vs baseline: 4.4834x; 1.1384x over previous
//
#include <hip/hip_runtime.h>
#include <math.h>
#include <stdint.h>

#define B_ 32
#define S_ 2048
#define D_ 1024
#define H_ 1024
#define NEGV -1000000000000.0f

typedef __attribute__((ext_vector_type(8))) short bf16x8;
typedef __attribute__((ext_vector_type(4))) float f32x4;

static __device__ __forceinline__ unsigned short f2bf(float x) {
    union { float f; unsigned u; } v; v.f = x;
    unsigned r = v.u + 0x7FFF + ((v.u >> 16) & 1);
    return (unsigned short)(r >> 16);
}
static __device__ __forceinline__ float bf2f(unsigned short h) {
    union { float f; unsigned u; } v; v.u = ((unsigned)h) << 16; return v.f;
}
static __device__ __forceinline__ float tanh_fast(float x) {
    float e = __expf(2.f * x);
    return 1.f - 2.f / (e + 1.f);
}
static __device__ __forceinline__ void gl_lds16(unsigned short* lds, const unsigned short* g) {
    __builtin_amdgcn_global_load_lds(
        (const __attribute__((address_space(1))) unsigned int*)(const void*)g,
        (__attribute__((address_space(3))) unsigned int*)(void*)lds,
        16, 0, 0);
}

// ---------- split We = W[:, D:] into bf16 hi/lo, CHUNK-SWIZZLED storage ----------
// within each 64-elem K-group: stored chunk c' = c ^ (row & 7)   (chunk = 8 elems = 16B)
__global__ __launch_bounds__(256) void k_splitW(const float* __restrict__ W,
                                                unsigned short* __restrict__ hi,
                                                unsigned short* __restrict__ lo) {
    int idx = blockIdx.x * 256 + threadIdx.x;   // 131072 chunks
    int h = idx >> 7, kc = idx & 127;           // kc: chunk within row (8 elems)
    const float* src = W + (size_t)h * (2 * D_) + D_ + kc * 8;
    float4 a = *(const float4*)src;
    float4 c4 = *(const float4*)(src + 4);
    float v[8] = {a.x, a.y, a.z, a.w, c4.x, c4.y, c4.z, c4.w};
    unsigned short th[8], tl[8];
#pragma unroll
    for (int j = 0; j < 8; ++j) {
        th[j] = f2bf(v[j]);
        tl[j] = f2bf(v[j] - bf2f(th[j]));
    }
    uint4 hw, lw;
    hw.x = th[0] | ((unsigned)th[1] << 16); hw.y = th[2] | ((unsigned)th[3] << 16);
    hw.z = th[4] | ((unsigned)th[5] << 16); hw.w = th[6] | ((unsigned)th[7] << 16);
    lw.x = tl[0] | ((unsigned)tl[1] << 16); lw.y = tl[2] | ((unsigned)tl[3] << 16);
    lw.z = tl[4] | ((unsigned)tl[5] << 16); lw.w = tl[6] | ((unsigned)tl[7] << 16);
    int g = kc >> 3, cc = kc & 7;
    int dst = g * 64 + ((cc ^ (h & 7)) << 3);
    *(uint4*)(hi + (size_t)h * D_ + dst) = hw;
    *(uint4*)(lo + (size_t)h * D_ + dst) = lw;
}

// ---------- split enc into bf16 hi/lo, CHUNK-SWIZZLED storage ----------
__global__ __launch_bounds__(256) void k_split_enc(const float* __restrict__ enc,
                                                   unsigned short* __restrict__ hi,
                                                   unsigned short* __restrict__ lo) {
    size_t gid = (size_t)blockIdx.x * 256 + threadIdx.x;   // 8Mi chunks
    size_t row = gid >> 7;
    int kc = (int)(gid & 127);
    const float* src = enc + row * D_ + kc * 8;
    float4 a = *(const float4*)src;
    float4 c4 = *(const float4*)(src + 4);
    float v[8] = {a.x, a.y, a.z, a.w, c4.x, c4.y, c4.z, c4.w};
    unsigned short th[8], tl[8];
#pragma unroll
    for (int j = 0; j < 8; ++j) {
        th[j] = f2bf(v[j]);
        tl[j] = f2bf(v[j] - bf2f(th[j]));
    }
    uint4 hw, lw;
    hw.x = th[0] | ((unsigned)th[1] << 16); hw.y = th[2] | ((unsigned)th[3] << 16);
    hw.z = th[4] | ((unsigned)th[5] << 16); hw.w = th[6] | ((unsigned)th[7] << 16);
    lw.x = tl[0] | ((unsigned)tl[1] << 16); lw.y = tl[2] | ((unsigned)tl[3] << 16);
    lw.z = tl[4] | ((unsigned)tl[5] << 16); lw.w = tl[6] | ((unsigned)tl[7] << 16);
    int g = kc >> 3, cc = kc & 7;
    int dst = g * 64 + ((cc ^ ((int)row & 7)) << 3);
    *(uint4*)(hi + row * D_ + dst) = hw;
    *(uint4*)(lo + row * D_ + dst) = lw;
}

// ---------- h_part ----------
__global__ __launch_bounds__(256) void k_hpart(const float* __restrict__ ls,
                                               const float* __restrict__ W,
                                               float* __restrict__ hp) {
    int bh = blockIdx.x * 256 + threadIdx.x;
    int b = bh >> 10, h = bh & 1023;
    const float* lsr = ls + b * D_;
    const float* wr  = W + (size_t)h * (2 * D_);
    float acc = 0.f;
#pragma unroll 4
    for (int d = 0; d < D_; d += 4) {
        float4 a = *(const float4*)(lsr + d);
        float4 w = *(const float4*)(wr + d);
        acc += a.x * w.x + a.y * w.y + a.z * w.z + a.w * w.w;
    }
    hp[bh] = acc;
}

// ---------- main GEMM: 256x256 tile, BK=64, 8-phase counted-vmcnt schedule ----------
// K'' = 3072 = 48 K-tiles: tile t -> (gd = t/3, plane p = t%3)
//   A plane: p<2 ? hi : lo ; B plane: p==1 ? lo : hi   =>  ahi*bhi + ahi*blo + alo*bhi
// grid 1024 = 256 mt x 4 nt, XCD-bijective swizzle.
__global__ __launch_bounds__(512, 2) void k_scores_8ph(
    const unsigned short* __restrict__ ench, const unsigned short* __restrict__ encl,
    const unsigned short* __restrict__ Whi,  const unsigned short* __restrict__ Wlo,
    const float* __restrict__ hp, const float* __restrict__ bias,
    const float* __restrict__ V, float* __restrict__ spart)
{
    extern __shared__ unsigned short smem[];     // 131072 B: A[2][256][64] | B[2][256][64]
    unsigned short* smemA = smem;                // slots at 0, 16384 shorts
    unsigned short* smemB = smem + 32768;        // slots at 0, 16384 shorts

    const int tid  = threadIdx.x;
    const int lane = tid & 63, wid = tid >> 6;
    const int wm = wid >> 2, wn = wid & 3;       // 2 x 4 waves
    const int l15 = lane & 15, lhi = lane >> 4;

    // XCD-bijective block swizzle (nwg = 1024, 128 per XCD)
    const int bid  = blockIdx.x;
    const int wgid = (bid & 7) * 128 + (bid >> 3);
    const int mt = wgid >> 2, nt = wgid & 3;
    const int m0 = mt * 256;
    const int nt256 = nt * 256;
    const int b = m0 >> 11;

    // per-lane staging source bases (element units)
    const size_t aoff = (size_t)(m0 + wid * 16 + (lane >> 3)) * D_ + (lane & 7) * 8;
    const size_t boff = (size_t)(nt256 + wid * 16 + (lane >> 3)) * D_ + (lane & 7) * 8;
    // per-wave LDS staging base (shorts), lane*16B added by HW
    const int ldsw = wid * 16 * 64;

    f32x4 acc[8][4];
#pragma unroll
    for (int i = 0; i < 8; ++i)
#pragma unroll
        for (int j = 0; j < 4; ++j)
            acc[i][j] = (f32x4){0.f, 0.f, 0.f, 0.f};

    // chunk-swizzled ds_read offsets: chunk' = (ks*4+lhi) ^ (l15&7)
    const int swz = l15 & 7;

#define STAGE_A(SLOT, HALF, SRC, KOFS) do {                                         \
    unsigned short* d_ = &smemA[(SLOT) * 16384 + (HALF) * 128 * 64 + ldsw];         \
    const unsigned short* s_ = (SRC) + aoff + (size_t)(HALF) * 131072 + (KOFS);     \
    gl_lds16(d_, s_);                                                               \
    gl_lds16(d_ + 512, s_ + 8192);                                                  \
} while (0)
#define STAGE_B(SLOT, HALF, SRC, KOFS) do {                                         \
    unsigned short* d_ = &smemB[(SLOT) * 16384 + (HALF) * 128 * 64 + ldsw];         \
    const unsigned short* s_ = (SRC) + boff + (size_t)(HALF) * 131072 + (KOFS);     \
    gl_lds16(d_, s_);                                                               \
    gl_lds16(d_ + 512, s_ + 8192);                                                  \
} while (0)

#define LDA(AR, CUR, MH, KS) do {                                                   \
    _Pragma("unroll")                                                               \
    for (int fi_ = 0; fi_ < 4; ++fi_) {                                             \
        int row_ = wm * 128 + (MH) * 64 + fi_ * 16 + l15;                           \
        int ch_  = ((KS) * 4 + lhi) ^ swz;                                          \
        AR[fi_] = *(const bf16x8*)&smemA[(CUR) * 16384 + row_ * 64 + ch_ * 8];      \
    }                                                                               \
} while (0)
#define LDB(BR, CUR, KS) do {                                                       \
    _Pragma("unroll")                                                               \
    for (int fi_ = 0; fi_ < 4; ++fi_) {                                             \
        int row_ = wn * 64 + fi_ * 16 + l15;                                        \
        int ch_  = ((KS) * 4 + lhi) ^ swz;                                          \
        BR[fi_] = *(const bf16x8*)&smemB[(CUR) * 16384 + row_ * 64 + ch_ * 8];      \
    }                                                                               \
} while (0)
#define MFMA16(AR, BR, MH) do {                                                     \
    __builtin_amdgcn_s_setprio(1);                                                  \
    _Pragma("unroll")                                                               \
    for (int fi_ = 0; fi_ < 4; ++fi_)                                               \
    _Pragma("unroll")                                                               \
        for (int fj_ = 0; fj_ < 4; ++fj_)                                           \
            acc[(MH) * 4 + fi_][fj_] = __builtin_amdgcn_mfma_f32_16x16x32_bf16(     \
                AR[fi_], BR[fj_], acc[(MH) * 4 + fi_][fj_], 0, 0, 0);               \
    __builtin_amdgcn_s_setprio(0);                                                  \
} while (0)

#define BAR()  asm volatile("s_barrier" ::: "memory")
#define VMC2() asm volatile("s_waitcnt vmcnt(2)" ::: "memory")

    // ---- prologue: stage tile 0 (gd=0, p=0: A=hi, B=hi) into slot 0
    STAGE_B(0, 0, Whi, 0);
    STAGE_B(0, 1, Whi, 0);
    STAGE_A(0, 0, ench, 0);
    STAGE_A(0, 1, ench, 0);
    VMC2();          // B0,B1,A0 of tile0 landed (A1 may be in flight)
    BAR();

    bf16x8 a[4], bk[4];
#pragma unroll 1
    for (int t = 0; t < 48; ++t) {
        const int cur = t & 1, nxt = cur ^ 1;
        const int tn = (t == 47) ? 0 : t + 1;     // dummy re-stage of tile0 at the end (never read)
        const int gd_n = tn / 3;
        const int p_n  = tn - gd_n * 3;
        const unsigned short* pa = (p_n < 2) ? ench : encl;
        const unsigned short* pb = (p_n == 1) ? Wlo : Whi;
        const int kofs = gd_n * 64;

        // ---- phase 0: (mh0, ks0); stage B-half0 of tile n
        LDB(bk, cur, 0);
        LDA(a, cur, 0, 0);
        STAGE_B(nxt, 0, pb, kofs);
        BAR();
        MFMA16(a, bk, 0);
        VMC2();      // A1(t) landed (B0(n) may be in flight)
        BAR();
        // ---- phase 1: (mh1, ks0); stage B-half1
        LDA(a, cur, 1, 0);
        STAGE_B(nxt, 1, pb, kofs);
        BAR();
        MFMA16(a, bk, 1);
        BAR();
        // ---- phase 2: (mh0, ks1); stage A-half0
        LDB(bk, cur, 1);
        LDA(a, cur, 0, 1);
        STAGE_A(nxt, 0, pa, kofs);
        BAR();
        MFMA16(a, bk, 0);
        BAR();
        // ---- phase 3: (mh1, ks1); stage A-half1
        LDA(a, cur, 1, 1);
        STAGE_A(nxt, 1, pa, kofs);
        BAR();
        MFMA16(a, bk, 1);
        VMC2();      // B0,B1,A0 of tile n landed
        BAR();
    }

    // ---- epilogue: tanh + V-weighted reduce
    float hb[4], vv[4];
#pragma unroll
    for (int fn = 0; fn < 4; ++fn) {
        int h = nt256 + wn * 64 + fn * 16 + l15;
        hb[fn] = hp[b * H_ + h] + bias[h];
        vv[fn] = V[h];
    }
    float* s_red = (float*)&smem[16384];   // A slot1 region (dummy stages hit slot0 only)
#pragma unroll
    for (int fm = 0; fm < 8; ++fm)
#pragma unroll
        for (int rg = 0; rg < 4; ++rg) {
            float rs = 0.f;
#pragma unroll
            for (int fn = 0; fn < 4; ++fn)
                rs += tanh_fast(acc[fm][fn][rg] + hb[fn]) * vv[fn];
            rs += __shfl_xor(rs, 1, 16);
            rs += __shfl_xor(rs, 2, 16);
            rs += __shfl_xor(rs, 4, 16);
            rs += __shfl_xor(rs, 8, 16);
            if (l15 == 0)
                s_red[wid * 128 + fm * 16 + lhi * 4 + rg] = rs;
        }
    __syncthreads();
    if (tid < 256) {
        int wmr = tid >> 7, rr = tid & 127;
        float v = s_red[(wmr * 4 + 0) * 128 + rr] + s_red[(wmr * 4 + 1) * 128 + rr]
                + s_red[(wmr * 4 + 2) * 128 + rr] + s_red[(wmr * 4 + 3) * 128 + rr];
        spart[(size_t)nt * 65536 + m0 + tid] = v;
    }
#undef STAGE_A
#undef STAGE_B
#undef LDA
#undef LDB
#undef MFMA16
#undef BAR
#undef VMC2
}

// ---------- fold nt-partials + mask + softmax ----------
__global__ __launch_bounds__(256) void k_softmax_fold(const float* __restrict__ spart,
                                                      const int* __restrict__ mask,
                                                      float* __restrict__ scores_out,
                                                      float* __restrict__ weights) {
    __shared__ float red[8];
    int b = blockIdx.x, tid = threadIdx.x;
    float vals[8];
    float mx = -INFINITY;
#pragma unroll
    for (int i = 0; i < 8; ++i) {
        int m = b * S_ + tid + i * 256;
        float s = spart[m] + spart[65536 + m] + spart[131072 + m] + spart[196608 + m];
        s = (mask[m] == 1) ? s : NEGV;
        scores_out[m] = s;
        vals[i] = s;
        mx = fmaxf(mx, s);
    }
    for (int off = 32; off; off >>= 1) mx = fmaxf(mx, __shfl_xor(mx, off, 64));
    int wave = tid >> 6;
    if ((tid & 63) == 0) red[wave] = mx;
    __syncthreads();
    mx = fmaxf(fmaxf(red[0], red[1]), fmaxf(red[2], red[3]));
    float sum = 0.f;
#pragma unroll
    for (int i = 0; i < 8; ++i) {
        vals[i] = expf(vals[i] - mx);
        sum += vals[i];
    }
    for (int off = 32; off; off >>= 1) sum += __shfl_xor(sum, off, 64);
    if ((tid & 63) == 0) red[4 + wave] = sum;
    __syncthreads();
    sum = red[4] + red[5] + red[6] + red[7];
    float inv = 1.f / sum;
#pragma unroll
    for (int i = 0; i < 8; ++i)
        weights[b * S_ + tid + i * 256] = vals[i] * inv;
}

// ---------- context ----------
__global__ __launch_bounds__(256) void k_ctx_partial(const float* __restrict__ weights,
                                                     const float* __restrict__ enc,
                                                     float* __restrict__ part) {
    int b = blockIdx.x >> 4;
    int chunk = blockIdx.x & 15;
    int tid = threadIdx.x;
    int d0 = tid * 4;
    float4 acc = {0.f, 0.f, 0.f, 0.f};
    int s0 = chunk * 128;
    const float* wrow = weights + b * S_;
    for (int s = s0; s < s0 + 128; ++s) {
        float w = wrow[s];
        if (w != 0.f) {
            float4 e = *(const float4*)(enc + (size_t)(b * S_ + s) * D_ + d0);
            acc.x += w * e.x; acc.y += w * e.y; acc.z += w * e.z; acc.w += w * e.w;
        }
    }
    *(float4*)(part + (size_t)blockIdx.x * D_ + d0) = acc;
}

__global__ __launch_bounds__(256) void k_ctx_reduce(const float* __restrict__ part,
                                                    float* __restrict__ ctx) {
    int bd = blockIdx.x * 256 + threadIdx.x;
    int b = bd >> 10, d = bd & 1023;
    float acc = 0.f;
#pragma unroll
    for (int c = 0; c < 16; ++c)
        acc += part[(size_t)(b * 16 + c) * D_ + d];
    ctx[bd] = acc;
}

// ================== fallback path (tiny ws): linear split + round-2 kernel ==================
__global__ __launch_bounds__(256) void k_splitW_lin(const float* __restrict__ W,
                                                    unsigned short* __restrict__ hi,
                                                    unsigned short* __restrict__ lo) {
    int idx = blockIdx.x * 256 + threadIdx.x;
    int h = idx >> 7, kc = idx & 127;
    const float* src = W + (size_t)h * (2 * D_) + D_ + kc * 8;
    float4 a = *(const float4*)src;
    float4 c = *(const float4*)(src + 4);
    float v[8] = {a.x, a.y, a.z, a.w, c.x, c.y, c.z, c.w};
    unsigned short th[8], tl[8];
#pragma unroll
    for (int j = 0; j < 8; ++j) {
        th[j] = f2bf(v[j]);
        tl[j] = f2bf(v[j] - bf2f(th[j]));
    }
    uint4 hw, lw;
    hw.x = th[0] | ((unsigned)th[1] << 16); hw.y = th[2] | ((unsigned)th[3] << 16);
    hw.z = th[4] | ((unsigned)th[5] << 16); hw.w = th[6] | ((unsigned)th[7] << 16);
    lw.x = tl[0] | ((unsigned)tl[1] << 16); lw.y = tl[2] | ((unsigned)tl[3] << 16);
    lw.z = tl[4] | ((unsigned)tl[5] << 16); lw.w = tl[6] | ((unsigned)tl[7] << 16);
    *(uint4*)(hi + (size_t)h * D_ + kc * 8) = hw;
    *(uint4*)(lo + (size_t)h * D_ + kc * 8) = lw;
}

__global__ __launch_bounds__(256, 2) void k_scores_mfma_fb(
    const float* __restrict__ enc,
    const unsigned short* __restrict__ Whi,
    const unsigned short* __restrict__ Wlo,
    const float* __restrict__ hp,
    const float* __restrict__ bias,
    const float* __restrict__ V,
    const int* __restrict__ mask,
    float* __restrict__ scores_out)
{
    __shared__ __align__(16) unsigned short smem[4 * 8192];
    unsigned short* sAhi = smem;
    unsigned short* sAlo = smem + 8192;
    unsigned short* sBhi = smem + 16384;
    unsigned short* sBlo = smem + 24576;

    const int tid  = threadIdx.x;
    const int lane = tid & 63, wid = tid >> 6;
    const int wr = wid >> 1, wc = wid & 1;
    const int l15 = lane & 15, lhi = lane >> 4;
    const int m0 = blockIdx.x * 128;
    const int b  = m0 >> 11;

    float rowsum[4][4] = {};
    float4 pa[8];
    uint4  pbh[4], pbl[4];

#define STAGE_LOAD(NB, KB) do {                                            \
    _Pragma("unroll")                                                      \
    for (int i_ = 0; i_ < 4; ++i_) {                                       \
        int c_ = tid + i_ * 256;                                           \
        int r_ = c_ >> 3, kc_ = c_ & 7;                                    \
        const float* ap_ = enc + (size_t)(m0 + r_) * D_ + (KB) * 64 + kc_ * 8; \
        pa[2 * i_]     = *(const float4*)ap_;                              \
        pa[2 * i_ + 1] = *(const float4*)(ap_ + 4);                        \
        size_t bo_ = (size_t)((NB) * 128 + r_) * D_ + (KB) * 64 + kc_ * 8; \
        pbh[i_] = *(const uint4*)(Whi + bo_);                              \
        pbl[i_] = *(const uint4*)(Wlo + bo_);                              \
    }                                                                      \
} while (0)

#define STAGE_WRITE() do {                                                 \
    _Pragma("unroll")                                                      \
    for (int i_ = 0; i_ < 4; ++i_) {                                       \
        int c_ = tid + i_ * 256;                                           \
        int sc_ = c_ ^ ((c_ >> 3) & 7);                                    \
        float vv_[8] = {pa[2*i_].x, pa[2*i_].y, pa[2*i_].z, pa[2*i_].w,    \
                        pa[2*i_+1].x, pa[2*i_+1].y, pa[2*i_+1].z, pa[2*i_+1].w}; \
        unsigned short th_[8], tl_[8];                                     \
        _Pragma("unroll")                                                  \
        for (int j_ = 0; j_ < 8; ++j_) {                                   \
            th_[j_] = f2bf(vv_[j_]);                                       \
            tl_[j_] = f2bf(vv_[j_] - bf2f(th_[j_]));                       \
        }                                                                  \
        uint4 hw_, lw_;                                                    \
        hw_.x = th_[0] | ((unsigned)th_[1] << 16); hw_.y = th_[2] | ((unsigned)th_[3] << 16); \
        hw_.z = th_[4] | ((unsigned)th_[5] << 16); hw_.w = th_[6] | ((unsigned)th_[7] << 16); \
        lw_.x = tl_[0] | ((unsigned)tl_[1] << 16); lw_.y = tl_[2] | ((unsigned)tl_[3] << 16); \
        lw_.z = tl_[4] | ((unsigned)tl_[5] << 16); lw_.w = tl_[6] | ((unsigned)tl_[7] << 16); \
        *(uint4*)&sAhi[sc_ * 8] = hw_;                                     \
        *(uint4*)&sAlo[sc_ * 8] = lw_;                                     \
        *(uint4*)&sBhi[sc_ * 8] = pbh[i_];                                 \
        *(uint4*)&sBlo[sc_ * 8] = pbl[i_];                                 \
    }                                                                      \
} while (0)

    STAGE_LOAD(0, 0);

    for (int nb = 0; nb < 8; ++nb) {
        f32x4 acc[4][4];
#pragma unroll
        for (int i = 0; i < 4; ++i)
#pragma unroll
            for (int j = 0; j < 4; ++j)
                acc[i][j] = (f32x4){0.f, 0.f, 0.f, 0.f};

        for (int kb = 0; kb < 16; ++kb) {
            __syncthreads();
            STAGE_WRITE();
            __syncthreads();
            int nkb = kb + 1, nnb = nb;
            if (nkb == 16) { nkb = 0; nnb = nb + 1; }
            if (nnb < 8) STAGE_LOAD(nnb, nkb);

#pragma unroll
            for (int ks = 0; ks < 2; ++ks) {
                bf16x8 bh[4], bl[4];
#pragma unroll
                for (int fn = 0; fn < 4; ++fn) {
                    int rB = wc * 64 + fn * 16 + l15;
                    int ch = (rB * 8 + ks * 4 + lhi) ^ (rB & 7);
                    bh[fn] = *(const bf16x8*)&sBhi[ch * 8];
                    bl[fn] = *(const bf16x8*)&sBlo[ch * 8];
                }
#pragma unroll
                for (int fm = 0; fm < 4; ++fm) {
                    int rA = wr * 64 + fm * 16 + l15;
                    int ch = (rA * 8 + ks * 4 + lhi) ^ (rA & 7);
                    bf16x8 ah = *(const bf16x8*)&sAhi[ch * 8];
                    bf16x8 al = *(const bf16x8*)&sAlo[ch * 8];
#pragma unroll
                    for (int fn = 0; fn < 4; ++fn) {
                        acc[fm][fn] = __builtin_amdgcn_mfma_f32_16x16x32_bf16(ah, bh[fn], acc[fm][fn], 0, 0, 0);
                        acc[fm][fn] = __builtin_amdgcn_mfma_f32_16x16x32_bf16(ah, bl[fn], acc[fm][fn], 0, 0, 0);
                        acc[fm][fn] = __builtin_amdgcn_mfma_f32_16x16x32_bf16(al, bh[fn], acc[fm][fn], 0, 0, 0);
                    }
                }
            }
        }

        int n0 = nb * 128;
#pragma unroll
        for (int fn = 0; fn < 4; ++fn) {
            int n = n0 + wc * 64 + fn * 16 + l15;
            float hbv = hp[b * H_ + n] + bias[n];
            float vvv = V[n];
#pragma unroll
            for (int fm = 0; fm < 4; ++fm) {
                f32x4 a = acc[fm][fn];
#pragma unroll
                for (int rg = 0; rg < 4; ++rg)
                    rowsum[fm][rg] += tanh_fast(a[rg] + hbv) * vvv;
            }
        }
    }

    __syncthreads();
    float* s_red = (float*)smem;
#pragma unroll
    for (int fm = 0; fm < 4; ++fm)
#pragma unroll
        for (int rg = 0; rg < 4; ++rg) {
            float v = rowsum[fm][rg];
            v += __shfl_xor(v, 1, 16);
            v += __shfl_xor(v, 2, 16);
            v += __shfl_xor(v, 4, 16);
            v += __shfl_xor(v, 8, 16);
            if (l15 == 0)
                s_red[wc * 128 + wr * 64 + fm * 16 + lhi * 4 + rg] = v;
        }
    __syncthreads();
    if (tid < 128) {
        int m = m0 + tid;
        float sc = s_red[tid] + s_red[128 + tid];
        scores_out[m] = (mask[m] == 1) ? sc : NEGV;
    }
#undef STAGE_LOAD
#undef STAGE_WRITE
}

__global__ __launch_bounds__(256) void k_softmax(const float* __restrict__ scores,
                                                 float* __restrict__ weights) {
    __shared__ float red[8];
    int b = blockIdx.x;
    int tid = threadIdx.x;
    const float* srow = scores + b * S_;
    float vals[8];
    float mx = -INFINITY;
#pragma unroll
    for (int i = 0; i < 8; ++i) {
        vals[i] = srow[tid + i * 256];
        mx = fmaxf(mx, vals[i]);
    }
    for (int off = 32; off; off >>= 1) mx = fmaxf(mx, __shfl_xor(mx, off, 64));
    int wave = tid >> 6;
    if ((tid & 63) == 0) red[wave] = mx;
    __syncthreads();
    mx = fmaxf(fmaxf(red[0], red[1]), fmaxf(red[2], red[3]));
    float sum = 0.f;
#pragma unroll
    for (int i = 0; i < 8; ++i) {
        vals[i] = expf(vals[i] - mx);
        sum += vals[i];
    }
    for (int off = 32; off; off >>= 1) sum += __shfl_xor(sum, off, 64);
    if ((tid & 63) == 0) red[4 + wave] = sum;
    __syncthreads();
    sum = red[4] + red[5] + red[6] + red[7];
    float inv = 1.f / sum;
#pragma unroll
    for (int i = 0; i < 8; ++i)
        weights[b * S_ + tid + i * 256] = vals[i] * inv;
}

extern "C" void kernel_launch(void* const* d_in, const int* in_sizes, int n_in,
                              void* d_out, int out_size, void* d_ws, size_t ws_size,
                              hipStream_t stream) {
    const float* ls   = (const float*)d_in[0];
    const float* enc  = (const float*)d_in[1];
    const int*   mask = (const int*)d_in[2];
    const float* W    = (const float*)d_in[3];
    const float* bias = (const float*)d_in[4];
    const float* V    = (const float*)d_in[5];

    float* out     = (float*)d_out;
    float* ctx     = out;
    float* weights = out + 32768;
    float* scores  = out + 98304;

    // fast-path workspace: ench(128MB) encl(128MB) Whi(2MB) Wlo(2MB) hp(128KB) spart(1MB) part(2MB)
    const size_t need = 268435456ull + 4194304ull + 131072ull + 1048576ull + 2097152ull;

    if (ws_size >= need) {
        unsigned short* ench = (unsigned short*)d_ws;
        unsigned short* encl = ench + 67108864;
        unsigned short* Whi  = encl + 67108864;
        unsigned short* Wlo  = Whi + 1048576;
        float* hp    = (float*)(Wlo + 1048576);
        float* spart = hp + 32768;              // 4 * 65536 floats
        float* part  = spart + 262144;          // 512 * 1024 floats

        hipFuncSetAttribute((const void*)k_scores_8ph,
                            hipFuncAttributeMaxDynamicSharedMemorySize, 131072);

        k_splitW<<<512, 256, 0, stream>>>(W, Whi, Wlo);
        k_split_enc<<<32768, 256, 0, stream>>>(enc, ench, encl);
        k_hpart<<<128, 256, 0, stream>>>(ls, W, hp);
        k_scores_8ph<<<1024, 512, 131072, stream>>>(ench, encl, Whi, Wlo, hp, bias, V, spart);
        k_softmax_fold<<<32, 256, 0, stream>>>(spart, mask, scores, weights);
        k_ctx_partial<<<512, 256, 0, stream>>>(weights, enc, part);
        k_ctx_reduce<<<128, 256, 0, stream>>>(part, ctx);
    } else {
        unsigned short* Whi = (unsigned short*)d_ws;
        unsigned short* Wlo = Whi + 1048576;
        float* hp   = (float*)(Wlo + 1048576);
        float* part = hp + 32768;

        k_splitW_lin<<<512, 256, 0, stream>>>(W, Whi, Wlo);
        k_hpart<<<128, 256, 0, stream>>>(ls, W, hp);
        k_scores_mfma_fb<<<512, 256, 0, stream>>>(enc, Whi, Wlo, hp, bias, V, mask, scores);
        k_softmax<<<32, 256, 0, stream>>>(scores, weights);
        k_ctx_partial<<<512, 256, 0, stream>>>(weights, enc, part);
        k_ctx_reduce<<<128, 256, 0, stream>>>(part, ctx);
    }
}

// Round 6
// 530.821 us; speedup vs baseline: 4.5129x; 1.0066x over previous
//
#include <hip/hip_runtime.h>
#include <math.h>
#include <stdint.h>

#define B_ 32
#define S_ 2048
#define D_ 1024
#define H_ 1024
#define NEGV -1000000000000.0f

typedef __attribute__((ext_vector_type(8))) short bf16x8;
typedef __attribute__((ext_vector_type(4))) float f32x4;

static __device__ __forceinline__ unsigned short f2bf(float x) {
    union { float f; unsigned u; } v; v.f = x;
    unsigned r = v.u + 0x7FFF + ((v.u >> 16) & 1);
    return (unsigned short)(r >> 16);
}
static __device__ __forceinline__ float bf2f(unsigned short h) {
    union { float f; unsigned u; } v; v.u = ((unsigned)h) << 16; return v.f;
}
static __device__ __forceinline__ float tanh_fast(float x) {
    float e = __expf(2.f * x);
    return 1.f - 2.f / (e + 1.f);
}
static __device__ __forceinline__ void gl_lds16(unsigned short* lds, const unsigned short* g) {
    __builtin_amdgcn_global_load_lds(
        (const __attribute__((address_space(1))) unsigned int*)(const void*)g,
        (__attribute__((address_space(3))) unsigned int*)(void*)lds,
        16, 0, 0);
}

// ---------- split We = W[:, D:] into bf16 hi/lo, CHUNK-SWIZZLED storage ----------
// within each 64-elem K-group: stored chunk c' = c ^ (row & 7)   (chunk = 8 elems = 16B)
__global__ __launch_bounds__(256) void k_splitW(const float* __restrict__ W,
                                                unsigned short* __restrict__ hi,
                                                unsigned short* __restrict__ lo) {
    int idx = blockIdx.x * 256 + threadIdx.x;   // 131072 chunks
    int h = idx >> 7, kc = idx & 127;           // kc: chunk within row (8 elems)
    const float* src = W + (size_t)h * (2 * D_) + D_ + kc * 8;
    float4 a = *(const float4*)src;
    float4 c4 = *(const float4*)(src + 4);
    float v[8] = {a.x, a.y, a.z, a.w, c4.x, c4.y, c4.z, c4.w};
    unsigned short th[8], tl[8];
#pragma unroll
    for (int j = 0; j < 8; ++j) {
        th[j] = f2bf(v[j]);
        tl[j] = f2bf(v[j] - bf2f(th[j]));
    }
    uint4 hw, lw;
    hw.x = th[0] | ((unsigned)th[1] << 16); hw.y = th[2] | ((unsigned)th[3] << 16);
    hw.z = th[4] | ((unsigned)th[5] << 16); hw.w = th[6] | ((unsigned)th[7] << 16);
    lw.x = tl[0] | ((unsigned)tl[1] << 16); lw.y = tl[2] | ((unsigned)tl[3] << 16);
    lw.z = tl[4] | ((unsigned)tl[5] << 16); lw.w = tl[6] | ((unsigned)tl[7] << 16);
    int g = kc >> 3, cc = kc & 7;
    int dst = g * 64 + ((cc ^ (h & 7)) << 3);
    *(uint4*)(hi + (size_t)h * D_ + dst) = hw;
    *(uint4*)(lo + (size_t)h * D_ + dst) = lw;
}

// ---------- split enc into bf16 hi/lo, CHUNK-SWIZZLED storage ----------
__global__ __launch_bounds__(256) void k_split_enc(const float* __restrict__ enc,
                                                   unsigned short* __restrict__ hi,
                                                   unsigned short* __restrict__ lo) {
    size_t gid = (size_t)blockIdx.x * 256 + threadIdx.x;   // 8Mi chunks
    size_t row = gid >> 7;
    int kc = (int)(gid & 127);
    const float* src = enc + row * D_ + kc * 8;
    float4 a = *(const float4*)src;
    float4 c4 = *(const float4*)(src + 4);
    float v[8] = {a.x, a.y, a.z, a.w, c4.x, c4.y, c4.z, c4.w};
    unsigned short th[8], tl[8];
#pragma unroll
    for (int j = 0; j < 8; ++j) {
        th[j] = f2bf(v[j]);
        tl[j] = f2bf(v[j] - bf2f(th[j]));
    }
    uint4 hw, lw;
    hw.x = th[0] | ((unsigned)th[1] << 16); hw.y = th[2] | ((unsigned)th[3] << 16);
    hw.z = th[4] | ((unsigned)th[5] << 16); hw.w = th[6] | ((unsigned)th[7] << 16);
    lw.x = tl[0] | ((unsigned)tl[1] << 16); lw.y = tl[2] | ((unsigned)tl[3] << 16);
    lw.z = tl[4] | ((unsigned)tl[5] << 16); lw.w = tl[6] | ((unsigned)tl[7] << 16);
    int g = kc >> 3, cc = kc & 7;
    int dst = g * 64 + ((cc ^ ((int)row & 7)) << 3);
    *(uint4*)(hi + row * D_ + dst) = hw;
    *(uint4*)(lo + row * D_ + dst) = lw;
}

// ---------- h_part ----------
__global__ __launch_bounds__(256) void k_hpart(const float* __restrict__ ls,
                                               const float* __restrict__ W,
                                               float* __restrict__ hp) {
    int bh = blockIdx.x * 256 + threadIdx.x;
    int b = bh >> 10, h = bh & 1023;
    const float* lsr = ls + b * D_;
    const float* wr  = W + (size_t)h * (2 * D_);
    float acc = 0.f;
#pragma unroll 4
    for (int d = 0; d < D_; d += 4) {
        float4 a = *(const float4*)(lsr + d);
        float4 w = *(const float4*)(wr + d);
        acc += a.x * w.x + a.y * w.y + a.z * w.z + a.w * w.w;
    }
    hp[bh] = acc;
}

// ---------- main GEMM: 256x256 tile, BK=64, double-buffered 2-phase schedule ----------
// K'' = 3072 = 48 K-tiles: tile t -> (gd = t/3, plane p = t%3)
//   A plane: p<2 ? hi : lo ; B plane: p==1 ? lo : hi   =>  ahi*bhi + ahi*blo + alo*bhi
// Pipeline: at iteration t start, issue ALL 8 global_load_lds for tile t+1 into
// slot nxt; compute tile t from slot cur (no intra-iteration barrier: writes go
// to nxt, reads hit cur); one __syncthreads (vmcnt0+lgkm0+barrier) per iteration
// makes every cross-wave stage->read dependency sound. (Race in r5's counted-
// vmcnt variant: phase-0 reads touched all 4 staged halves, vmcnt(2) left 2 in
// flight.)
__global__ __launch_bounds__(512, 2) void k_scores_2ph(
    const unsigned short* __restrict__ ench, const unsigned short* __restrict__ encl,
    const unsigned short* __restrict__ Whi,  const unsigned short* __restrict__ Wlo,
    const float* __restrict__ hp, const float* __restrict__ bias,
    const float* __restrict__ V, float* __restrict__ spart)
{
    extern __shared__ unsigned short smem[];     // 131072 B: A[2][256][64] | B[2][256][64]
    unsigned short* smemA = smem;                // slots at 0, 16384 shorts
    unsigned short* smemB = smem + 32768;        // slots at 0, 16384 shorts

    const int tid  = threadIdx.x;
    const int lane = tid & 63, wid = tid >> 6;
    const int wm = wid >> 2, wn = wid & 3;       // 2 x 4 waves
    const int l15 = lane & 15, lhi = lane >> 4;

    // XCD-bijective block swizzle (nwg = 1024, 128 per XCD)
    const int bid  = blockIdx.x;
    const int wgid = (bid & 7) * 128 + (bid >> 3);
    const int mt = wgid >> 2, nt = wgid & 3;
    const int m0 = mt * 256;
    const int nt256 = nt * 256;
    const int b = m0 >> 11;

    // per-lane staging source bases (element units)
    const size_t aoff = (size_t)(m0 + wid * 16 + (lane >> 3)) * D_ + (lane & 7) * 8;
    const size_t boff = (size_t)(nt256 + wid * 16 + (lane >> 3)) * D_ + (lane & 7) * 8;
    // per-wave LDS staging base (shorts), lane*16B added by HW
    const int ldsw = wid * 16 * 64;

    f32x4 acc[8][4];
#pragma unroll
    for (int i = 0; i < 8; ++i)
#pragma unroll
        for (int j = 0; j < 4; ++j)
            acc[i][j] = (f32x4){0.f, 0.f, 0.f, 0.f};

    // chunk-swizzled ds_read: stored chunk = logical ^ (row&7); row&7 == l15&7
    const int swz = l15 & 7;

#define STAGE_A(SLOT, HALF, SRC, KOFS) do {                                         \
    unsigned short* d_ = &smemA[(SLOT) * 16384 + (HALF) * 8192 + ldsw];             \
    const unsigned short* s_ = (SRC) + aoff + (size_t)(HALF) * 131072 + (KOFS);     \
    gl_lds16(d_, s_);                                                               \
    gl_lds16(d_ + 512, s_ + 8192);                                                  \
} while (0)
#define STAGE_B(SLOT, HALF, SRC, KOFS) do {                                         \
    unsigned short* d_ = &smemB[(SLOT) * 16384 + (HALF) * 8192 + ldsw];             \
    const unsigned short* s_ = (SRC) + boff + (size_t)(HALF) * 131072 + (KOFS);     \
    gl_lds16(d_, s_);                                                               \
    gl_lds16(d_ + 512, s_ + 8192);                                                  \
} while (0)

#define LDA(AR, CUR, MH, KS) do {                                                   \
    _Pragma("unroll")                                                               \
    for (int fi_ = 0; fi_ < 4; ++fi_) {                                             \
        int row_ = wm * 128 + (MH) * 64 + fi_ * 16 + l15;                           \
        int ch_  = ((KS) * 4 + lhi) ^ swz;                                          \
        AR[fi_] = *(const bf16x8*)&smemA[(CUR) * 16384 + row_ * 64 + ch_ * 8];      \
    }                                                                               \
} while (0)
#define LDB(BR, CUR, KS) do {                                                       \
    _Pragma("unroll")                                                               \
    for (int fi_ = 0; fi_ < 4; ++fi_) {                                             \
        int row_ = wn * 64 + fi_ * 16 + l15;                                        \
        int ch_  = ((KS) * 4 + lhi) ^ swz;                                          \
        BR[fi_] = *(const bf16x8*)&smemB[(CUR) * 16384 + row_ * 64 + ch_ * 8];      \
    }                                                                               \
} while (0)
#define MFMA16(AR, BR, MH) do {                                                     \
    __builtin_amdgcn_s_setprio(1);                                                  \
    _Pragma("unroll")                                                               \
    for (int fi_ = 0; fi_ < 4; ++fi_)                                               \
    _Pragma("unroll")                                                               \
        for (int fj_ = 0; fj_ < 4; ++fj_)                                           \
            acc[(MH) * 4 + fi_][fj_] = __builtin_amdgcn_mfma_f32_16x16x32_bf16(     \
                AR[fi_], BR[fj_], acc[(MH) * 4 + fi_][fj_], 0, 0, 0);               \
    __builtin_amdgcn_s_setprio(0);                                                  \
} while (0)

    // ---- prologue: stage tile 0 (gd=0, p=0: A=hi, B=hi) into slot 0
    STAGE_B(0, 0, Whi, 0);
    STAGE_B(0, 1, Whi, 0);
    STAGE_A(0, 0, ench, 0);
    STAGE_A(0, 1, ench, 0);
    __syncthreads();                      // vmcnt(0)+lgkmcnt(0)+barrier: tile0 visible

    bf16x8 a[4], bk[4];
#pragma unroll 1
    for (int t = 0; t < 48; ++t) {
        const int cur = t & 1, nxt = cur ^ 1;

        // ---- issue ALL stage loads for tile t+1 first (land during compute)
        if (t < 47) {
            const int tn   = t + 1;
            const int gd_n = tn / 3;
            const int p_n  = tn - gd_n * 3;
            const unsigned short* pa = (p_n < 2) ? ench : encl;
            const unsigned short* pb = (p_n == 1) ? Wlo : Whi;
            const int kofs = gd_n * 64;
            STAGE_B(nxt, 0, pb, kofs);
            STAGE_B(nxt, 1, pb, kofs);
            STAGE_A(nxt, 0, pa, kofs);
            STAGE_A(nxt, 1, pa, kofs);
        }

        // ---- compute tile t from slot cur (4 quadrants, 64 MFMA/wave)
#pragma unroll
        for (int ks = 0; ks < 2; ++ks) {
            LDB(bk, cur, ks);
            LDA(a, cur, 0, ks);
            MFMA16(a, bk, 0);
            LDA(a, cur, 1, ks);
            MFMA16(a, bk, 1);
        }

        __syncthreads();   // t+1 loads drained; all reads of cur done -> slot reuse safe
    }

    // ---- epilogue: tanh + V-weighted reduce
    float hb[4], vv[4];
#pragma unroll
    for (int fn = 0; fn < 4; ++fn) {
        int h = nt256 + wn * 64 + fn * 16 + l15;
        hb[fn] = hp[b * H_ + h] + bias[h];
        vv[fn] = V[h];
    }
    float* s_red = (float*)smem;          // all staging complete after final barrier
#pragma unroll
    for (int fm = 0; fm < 8; ++fm)
#pragma unroll
        for (int rg = 0; rg < 4; ++rg) {
            float rs = 0.f;
#pragma unroll
            for (int fn = 0; fn < 4; ++fn)
                rs += tanh_fast(acc[fm][fn][rg] + hb[fn]) * vv[fn];
            rs += __shfl_xor(rs, 1, 16);
            rs += __shfl_xor(rs, 2, 16);
            rs += __shfl_xor(rs, 4, 16);
            rs += __shfl_xor(rs, 8, 16);
            if (l15 == 0)
                s_red[wid * 128 + fm * 16 + lhi * 4 + rg] = rs;
        }
    __syncthreads();
    if (tid < 256) {
        int wmr = tid >> 7, rr = tid & 127;
        float v = s_red[(wmr * 4 + 0) * 128 + rr] + s_red[(wmr * 4 + 1) * 128 + rr]
                + s_red[(wmr * 4 + 2) * 128 + rr] + s_red[(wmr * 4 + 3) * 128 + rr];
        spart[(size_t)nt * 65536 + m0 + tid] = v;
    }
#undef STAGE_A
#undef STAGE_B
#undef LDA
#undef LDB
#undef MFMA16
}

// ---------- fold nt-partials + mask + softmax ----------
__global__ __launch_bounds__(256) void k_softmax_fold(const float* __restrict__ spart,
                                                      const int* __restrict__ mask,
                                                      float* __restrict__ scores_out,
                                                      float* __restrict__ weights) {
    __shared__ float red[8];
    int b = blockIdx.x, tid = threadIdx.x;
    float vals[8];
    float mx = -INFINITY;
#pragma unroll
    for (int i = 0; i < 8; ++i) {
        int m = b * S_ + tid + i * 256;
        float s = spart[m] + spart[65536 + m] + spart[131072 + m] + spart[196608 + m];
        s = (mask[m] == 1) ? s : NEGV;
        scores_out[m] = s;
        vals[i] = s;
        mx = fmaxf(mx, s);
    }
    for (int off = 32; off; off >>= 1) mx = fmaxf(mx, __shfl_xor(mx, off, 64));
    int wave = tid >> 6;
    if ((tid & 63) == 0) red[wave] = mx;
    __syncthreads();
    mx = fmaxf(fmaxf(red[0], red[1]), fmaxf(red[2], red[3]));
    float sum = 0.f;
#pragma unroll
    for (int i = 0; i < 8; ++i) {
        vals[i] = expf(vals[i] - mx);
        sum += vals[i];
    }
    for (int off = 32; off; off >>= 1) sum += __shfl_xor(sum, off, 64);
    if ((tid & 63) == 0) red[4 + wave] = sum;
    __syncthreads();
    sum = red[4] + red[5] + red[6] + red[7];
    float inv = 1.f / sum;
#pragma unroll
    for (int i = 0; i < 8; ++i)
        weights[b * S_ + tid + i * 256] = vals[i] * inv;
}

// ---------- context ----------
__global__ __launch_bounds__(256) void k_ctx_partial(const float* __restrict__ weights,
                                                     const float* __restrict__ enc,
                                                     float* __restrict__ part) {
    int b = blockIdx.x >> 4;
    int chunk = blockIdx.x & 15;
    int tid = threadIdx.x;
    int d0 = tid * 4;
    float4 acc = {0.f, 0.f, 0.f, 0.f};
    int s0 = chunk * 128;
    const float* wrow = weights + b * S_;
    for (int s = s0; s < s0 + 128; ++s) {
        float w = wrow[s];
        if (w != 0.f) {
            float4 e = *(const float4*)(enc + (size_t)(b * S_ + s) * D_ + d0);
            acc.x += w * e.x; acc.y += w * e.y; acc.z += w * e.z; acc.w += w * e.w;
        }
    }
    *(float4*)(part + (size_t)blockIdx.x * D_ + d0) = acc;
}

__global__ __launch_bounds__(256) void k_ctx_reduce(const float* __restrict__ part,
                                                    float* __restrict__ ctx) {
    int bd = blockIdx.x * 256 + threadIdx.x;
    int b = bd >> 10, d = bd & 1023;
    float acc = 0.f;
#pragma unroll
    for (int c = 0; c < 16; ++c)
        acc += part[(size_t)(b * 16 + c) * D_ + d];
    ctx[bd] = acc;
}

// ================== fallback path (tiny ws): linear split + round-2 kernel ==================
__global__ __launch_bounds__(256) void k_splitW_lin(const float* __restrict__ W,
                                                    unsigned short* __restrict__ hi,
                                                    unsigned short* __restrict__ lo) {
    int idx = blockIdx.x * 256 + threadIdx.x;
    int h = idx >> 7, kc = idx & 127;
    const float* src = W + (size_t)h * (2 * D_) + D_ + kc * 8;
    float4 a = *(const float4*)src;
    float4 c = *(const float4*)(src + 4);
    float v[8] = {a.x, a.y, a.z, a.w, c.x, c.y, c.z, c.w};
    unsigned short th[8], tl[8];
#pragma unroll
    for (int j = 0; j < 8; ++j) {
        th[j] = f2bf(v[j]);
        tl[j] = f2bf(v[j] - bf2f(th[j]));
    }
    uint4 hw, lw;
    hw.x = th[0] | ((unsigned)th[1] << 16); hw.y = th[2] | ((unsigned)th[3] << 16);
    hw.z = th[4] | ((unsigned)th[5] << 16); hw.w = th[6] | ((unsigned)th[7] << 16);
    lw.x = tl[0] | ((unsigned)tl[1] << 16); lw.y = tl[2] | ((unsigned)tl[3] << 16);
    lw.z = tl[4] | ((unsigned)tl[5] << 16); lw.w = tl[6] | ((unsigned)tl[7] << 16);
    *(uint4*)(hi + (size_t)h * D_ + kc * 8) = hw;
    *(uint4*)(lo + (size_t)h * D_ + kc * 8) = lw;
}

__global__ __launch_bounds__(256, 2) void k_scores_mfma_fb(
    const float* __restrict__ enc,
    const unsigned short* __restrict__ Whi,
    const unsigned short* __restrict__ Wlo,
    const float* __restrict__ hp,
    const float* __restrict__ bias,
    const float* __restrict__ V,
    const int* __restrict__ mask,
    float* __restrict__ scores_out)
{
    __shared__ __align__(16) unsigned short smem[4 * 8192];
    unsigned short* sAhi = smem;
    unsigned short* sAlo = smem + 8192;
    unsigned short* sBhi = smem + 16384;
    unsigned short* sBlo = smem + 24576;

    const int tid  = threadIdx.x;
    const int lane = tid & 63, wid = tid >> 6;
    const int wr = wid >> 1, wc = wid & 1;
    const int l15 = lane & 15, lhi = lane >> 4;
    const int m0 = blockIdx.x * 128;
    const int b  = m0 >> 11;

    float rowsum[4][4] = {};
    float4 pa[8];
    uint4  pbh[4], pbl[4];

#define STAGE_LOAD(NB, KB) do {                                            \
    _Pragma("unroll")                                                      \
    for (int i_ = 0; i_ < 4; ++i_) {                                       \
        int c_ = tid + i_ * 256;                                           \
        int r_ = c_ >> 3, kc_ = c_ & 7;                                    \
        const float* ap_ = enc + (size_t)(m0 + r_) * D_ + (KB) * 64 + kc_ * 8; \
        pa[2 * i_]     = *(const float4*)ap_;                              \
        pa[2 * i_ + 1] = *(const float4*)(ap_ + 4);                        \
        size_t bo_ = (size_t)((NB) * 128 + r_) * D_ + (KB) * 64 + kc_ * 8; \
        pbh[i_] = *(const uint4*)(Whi + bo_);                              \
        pbl[i_] = *(const uint4*)(Wlo + bo_);                              \
    }                                                                      \
} while (0)

#define STAGE_WRITE() do {                                                 \
    _Pragma("unroll")                                                      \
    for (int i_ = 0; i_ < 4; ++i_) {                                       \
        int c_ = tid + i_ * 256;                                           \
        int sc_ = c_ ^ ((c_ >> 3) & 7);                                    \
        float vv_[8] = {pa[2*i_].x, pa[2*i_].y, pa[2*i_].z, pa[2*i_].w,    \
                        pa[2*i_+1].x, pa[2*i_+1].y, pa[2*i_+1].z, pa[2*i_+1].w}; \
        unsigned short th_[8], tl_[8];                                     \
        _Pragma("unroll")                                                  \
        for (int j_ = 0; j_ < 8; ++j_) {                                   \
            th_[j_] = f2bf(vv_[j_]);                                       \
            tl_[j_] = f2bf(vv_[j_] - bf2f(th_[j_]));                       \
        }                                                                  \
        uint4 hw_, lw_;                                                    \
        hw_.x = th_[0] | ((unsigned)th_[1] << 16); hw_.y = th_[2] | ((unsigned)th_[3] << 16); \
        hw_.z = th_[4] | ((unsigned)th_[5] << 16); hw_.w = th_[6] | ((unsigned)th_[7] << 16); \
        lw_.x = tl_[0] | ((unsigned)tl_[1] << 16); lw_.y = tl_[2] | ((unsigned)tl_[3] << 16); \
        lw_.z = tl_[4] | ((unsigned)tl_[5] << 16); lw_.w = tl_[6] | ((unsigned)tl_[7] << 16); \
        *(uint4*)&sAhi[sc_ * 8] = hw_;                                     \
        *(uint4*)&sAlo[sc_ * 8] = lw_;                                     \
        *(uint4*)&sBhi[sc_ * 8] = pbh[i_];                                 \
        *(uint4*)&sBlo[sc_ * 8] = pbl[i_];                                 \
    }                                                                      \
} while (0)

    STAGE_LOAD(0, 0);

    for (int nb = 0; nb < 8; ++nb) {
        f32x4 acc[4][4];
#pragma unroll
        for (int i = 0; i < 4; ++i)
#pragma unroll
            for (int j = 0; j < 4; ++j)
                acc[i][j] = (f32x4){0.f, 0.f, 0.f, 0.f};

        for (int kb = 0; kb < 16; ++kb) {
            __syncthreads();
            STAGE_WRITE();
            __syncthreads();
            int nkb = kb + 1, nnb = nb;
            if (nkb == 16) { nkb = 0; nnb = nb + 1; }
            if (nnb < 8) STAGE_LOAD(nnb, nkb);

#pragma unroll
            for (int ks = 0; ks < 2; ++ks) {
                bf16x8 bh[4], bl[4];
#pragma unroll
                for (int fn = 0; fn < 4; ++fn) {
                    int rB = wc * 64 + fn * 16 + l15;
                    int ch = (rB * 8 + ks * 4 + lhi) ^ (rB & 7);
                    bh[fn] = *(const bf16x8*)&sBhi[ch * 8];
                    bl[fn] = *(const bf16x8*)&sBlo[ch * 8];
                }
#pragma unroll
                for (int fm = 0; fm < 4; ++fm) {
                    int rA = wr * 64 + fm * 16 + l15;
                    int ch = (rA * 8 + ks * 4 + lhi) ^ (rA & 7);
                    bf16x8 ah = *(const bf16x8*)&sAhi[ch * 8];
                    bf16x8 al = *(const bf16x8*)&sAlo[ch * 8];
#pragma unroll
                    for (int fn = 0; fn < 4; ++fn) {
                        acc[fm][fn] = __builtin_amdgcn_mfma_f32_16x16x32_bf16(ah, bh[fn], acc[fm][fn], 0, 0, 0);
                        acc[fm][fn] = __builtin_amdgcn_mfma_f32_16x16x32_bf16(ah, bl[fn], acc[fm][fn], 0, 0, 0);
                        acc[fm][fn] = __builtin_amdgcn_mfma_f32_16x16x32_bf16(al, bh[fn], acc[fm][fn], 0, 0, 0);
                    }
                }
            }
        }

        int n0 = nb * 128;
#pragma unroll
        for (int fn = 0; fn < 4; ++fn) {
            int n = n0 + wc * 64 + fn * 16 + l15;
            float hbv = hp[b * H_ + n] + bias[n];
            float vvv = V[n];
#pragma unroll
            for (int fm = 0; fm < 4; ++fm) {
                f32x4 a = acc[fm][fn];
#pragma unroll
                for (int rg = 0; rg < 4; ++rg)
                    rowsum[fm][rg] += tanh_fast(a[rg] + hbv) * vvv;
            }
        }
    }

    __syncthreads();
    float* s_red = (float*)smem;
#pragma unroll
    for (int fm = 0; fm < 4; ++fm)
#pragma unroll
        for (int rg = 0; rg < 4; ++rg) {
            float v = rowsum[fm][rg];
            v += __shfl_xor(v, 1, 16);
            v += __shfl_xor(v, 2, 16);
            v += __shfl_xor(v, 4, 16);
            v += __shfl_xor(v, 8, 16);
            if (l15 == 0)
                s_red[wc * 128 + wr * 64 + fm * 16 + lhi * 4 + rg] = v;
        }
    __syncthreads();
    if (tid < 128) {
        int m = m0 + tid;
        float sc = s_red[tid] + s_red[128 + tid];
        scores_out[m] = (mask[m] == 1) ? sc : NEGV;
    }
#undef STAGE_LOAD
#undef STAGE_WRITE
}

__global__ __launch_bounds__(256) void k_softmax(const float* __restrict__ scores,
                                                 float* __restrict__ weights) {
    __shared__ float red[8];
    int b = blockIdx.x;
    int tid = threadIdx.x;
    const float* srow = scores + b * S_;
    float vals[8];
    float mx = -INFINITY;
#pragma unroll
    for (int i = 0; i < 8; ++i) {
        vals[i] = srow[tid + i * 256];
        mx = fmaxf(mx, vals[i]);
    }
    for (int off = 32; off; off >>= 1) mx = fmaxf(mx, __shfl_xor(mx, off, 64));
    int wave = tid >> 6;
    if ((tid & 63) == 0) red[wave] = mx;
    __syncthreads();
    mx = fmaxf(fmaxf(red[0], red[1]), fmaxf(red[2], red[3]));
    float sum = 0.f;
#pragma unroll
    for (int i = 0; i < 8; ++i) {
        vals[i] = expf(vals[i] - mx);
        sum += vals[i];
    }
    for (int off = 32; off; off >>= 1) sum += __shfl_xor(sum, off, 64);
    if ((tid & 63) == 0) red[4 + wave] = sum;
    __syncthreads();
    sum = red[4] + red[5] + red[6] + red[7];
    float inv = 1.f / sum;
#pragma unroll
    for (int i = 0; i < 8; ++i)
        weights[b * S_ + tid + i * 256] = vals[i] * inv;
}

extern "C" void kernel_launch(void* const* d_in, const int* in_sizes, int n_in,
                              void* d_out, int out_size, void* d_ws, size_t ws_size,
                              hipStream_t stream) {
    const float* ls   = (const float*)d_in[0];
    const float* enc  = (const float*)d_in[1];
    const int*   mask = (const int*)d_in[2];
    const float* W    = (const float*)d_in[3];
    const float* bias = (const float*)d_in[4];
    const float* V    = (const float*)d_in[5];

    float* out     = (float*)d_out;
    float* ctx     = out;
    float* weights = out + 32768;
    float* scores  = out + 98304;

    // fast-path workspace: ench(128MB) encl(128MB) Whi(2MB) Wlo(2MB) hp(128KB) spart(1MB) part(2MB)
    const size_t need = 268435456ull + 4194304ull + 131072ull + 1048576ull + 2097152ull;

    if (ws_size >= need) {
        unsigned short* ench = (unsigned short*)d_ws;
        unsigned short* encl = ench + 67108864;
        unsigned short* Whi  = encl + 67108864;
        unsigned short* Wlo  = Whi + 1048576;
        float* hp    = (float*)(Wlo + 1048576);
        float* spart = hp + 32768;              // 4 * 65536 floats
        float* part  = spart + 262144;          // 512 * 1024 floats

        hipFuncSetAttribute((const void*)k_scores_2ph,
                            hipFuncAttributeMaxDynamicSharedMemorySize, 131072);

        k_splitW<<<512, 256, 0, stream>>>(W, Whi, Wlo);
        k_split_enc<<<32768, 256, 0, stream>>>(enc, ench, encl);
        k_hpart<<<128, 256, 0, stream>>>(ls, W, hp);
        k_scores_2ph<<<1024, 512, 131072, stream>>>(ench, encl, Whi, Wlo, hp, bias, V, spart);
        k_softmax_fold<<<32, 256, 0, stream>>>(spart, mask, scores, weights);
        k_ctx_partial<<<512, 256, 0, stream>>>(weights, enc, part);
        k_ctx_reduce<<<128, 256, 0, stream>>>(part, ctx);
    } else {
        unsigned short* Whi = (unsigned short*)d_ws;
        unsigned short* Wlo = Whi + 1048576;
        float* hp   = (float*)(Wlo + 1048576);
        float* part = hp + 32768;

        k_splitW_lin<<<512, 256, 0, stream>>>(W, Whi, Wlo);
        k_hpart<<<128, 256, 0, stream>>>(ls, W, hp);
        k_scores_mfma_fb<<<512, 256, 0, stream>>>(enc, Whi, Wlo, hp, bias, V, mask, scores);
        k_softmax<<<32, 256, 0, stream>>>(scores, weights);
        k_ctx_partial<<<512, 256, 0, stream>>>(weights, enc, part);
        k_ctx_reduce<<<128, 256, 0, stream>>>(part, ctx);
    }
}